// Round 2
// baseline (370.646 us; speedup 1.0000x reference)
//
#include <hip/hip_runtime.h>
#include <hip/hip_bf16.h>
#include <stdint.h>

#define DEVI static __device__ __forceinline__

typedef __attribute__((ext_vector_type(4))) float f32x4;
typedef __attribute__((ext_vector_type(8))) short bf16x8;
typedef unsigned short u16;
typedef unsigned int u32;

// B=16, N=4096, C=384, H=8, D=48
#define BB 16
#define NN 4096
#define CC 384
#define HH 8
#define DD 48

DEVI u16 f2bf(float f) {
  union { float f; u32 u; } c; c.f = f;
  u32 u = c.u;
  u32 r = (u + 0x7FFFu + ((u >> 16) & 1u)) >> 16;
  return (u16)r;
}

DEVI void stage8(u16* dst, const float* src) {
  const f32x4 a = *(const f32x4*)(src);
  const f32x4 b = *(const f32x4*)(src + 4);
  union { bf16x8 v; u16 u[8]; } o;
  o.u[0] = f2bf(a[0]); o.u[1] = f2bf(a[1]); o.u[2] = f2bf(a[2]); o.u[3] = f2bf(a[3]);
  o.u[4] = f2bf(b[0]); o.u[5] = f2bf(b[1]); o.u[6] = f2bf(b[2]); o.u[7] = f2bf(b[3]);
  *(bf16x8*)dst = o.v;
}
DEVI void store_out(float* p, float v) { *p = v; }
DEVI void store_out(u16* p, float v) { *p = f2bf(v); }

// async global->LDS, 16B per lane. LDS dest must be linear: base + lane*16.
typedef const __attribute__((address_space(1))) void* gas_ptr;
typedef __attribute__((address_space(3))) void* las_ptr;
DEVI void gload16(const void* g, void* l) {
  __builtin_amdgcn_global_load_lds((gas_ptr)g, (las_ptr)l, 16, 0, 0);
}

// ============================================================================
// fp32 -> bf16 bulk convert (x and wp)
// ============================================================================
__global__ __launch_bounds__(256)
void f32_to_bf16(const float* __restrict__ in, u16* __restrict__ out, int n8) {
  const int i = blockIdx.x * 256 + threadIdx.x;
  if (i >= n8) return;
  stage8(out + (size_t)i * 8, in + (size_t)i * 8);
}

// ============================================================================
// Fused-weight precompute: W'[o][c] = sum_m wtop[o][m]*cw[m][c]
//                          b'[o]    = btop[o] + sum_m wtop[o][m]*cb[m]
// 16 o-rows per block (72 blocks) so cw is read 72x, not 1152x.
// ============================================================================
__global__ __launch_bounds__(384)
void fuse_weights(const float* __restrict__ cw, const float* __restrict__ cb,
                  const float* __restrict__ wq, const float* __restrict__ bq,
                  const float* __restrict__ wkv, const float* __restrict__ bkv,
                  u16* __restrict__ Wf, float* __restrict__ bf_) {
  const int o0 = blockIdx.x * 16;           // 0,16,...,1136 ; side-uniform (384%16==0)
  const int c = threadIdx.x;                // 0..383
  const float* wbase;
  const float* btop;
  if (o0 < CC) { wbase = wq + (size_t)o0 * CC;        btop = bq + o0; }
  else         { wbase = wkv + (size_t)(o0 - CC) * CC; btop = bkv + (o0 - CC); }
  float acc[16] = {};
  for (int m = 0; m < CC; ++m) {
    const float v = cw[(size_t)m * CC + c];
#pragma unroll
    for (int oo = 0; oo < 16; ++oo) acc[oo] += wbase[oo * CC + m] * v;
  }
#pragma unroll
  for (int oo = 0; oo < 16; ++oo) Wf[(size_t)(o0 + oo) * CC + c] = f2bf(acc[oo]);
  if (c < 16) {
    float s = btop[c];
    for (int m = 0; m < CC; ++m) s += wbase[c * CC + m] * cb[m];
    bf_[o0 + c] = s;
  }
}

// ============================================================================
// GEMM: C[M,N] = A[M,K] @ W[N,K]^T + bias[N]   (bf16 in, fp32 accumulate)
// BM=BN=128, BK=64; 4 waves (2x2) each own 64x64. global_load_lds width=16
// staging into LINEAR LDS (no pad -- required by gload_lds).
// ============================================================================
template<typename OT>
__global__ __launch_bounds__(256)
void gemm_bt16(const u16* __restrict__ A, const u16* __restrict__ W,
               const float* __restrict__ bias, OT* __restrict__ C,
               int M, int N, int K) {
  constexpr int BM = 128, BN = 128, BK = 64;
  __shared__ __align__(16) u16 As[BM * BK];
  __shared__ __align__(16) u16 Bs[BN * BK];

  const int bn = blockIdx.x, bm = blockIdx.y;   // bn fastest -> A-tile L2/L3 reuse
  const int t = threadIdx.x;
  const int wid = t >> 6, lane = t & 63;
  const int wr = wid >> 1, wc = wid & 1;
  const int row0 = bm * BM, col0 = bn * BN;
  const int lrow = lane & 15;

  // staging coords: thread t loads 16B: row = t>>3 (+32 per it), col8 = (t&7)*8
  const int arow = t >> 3, acol = (t & 7) * 8;
  const u16* Ag = A + (size_t)(row0 + arow) * K + acol;
  const u16* Wg = W + (size_t)(col0 + arow) * K + acol;
  u16* Al = As + t * 8;
  u16* Bl = Bs + t * 8;

  f32x4 acc[4][4] = {};

  for (int k0 = 0; k0 < K; k0 += BK) {
    __syncthreads();
#pragma unroll
    for (int it = 0; it < 4; ++it) {
      gload16(Ag + (size_t)(it * 32) * K + k0, Al + it * 2048);
      gload16(Wg + (size_t)(it * 32) * K + k0, Bl + it * 2048);
    }
    __syncthreads();   // drains vmcnt(0): staged tiles visible
#pragma unroll
    for (int kk = 0; kk < 2; ++kk) {
      const int lk = kk * 32 + (lane >> 4) * 8;
      bf16x8 af[4], bf[4];
#pragma unroll
      for (int i = 0; i < 4; ++i)
        af[i] = *(const bf16x8*)&As[(wr * 64 + i * 16 + lrow) * BK + lk];
#pragma unroll
      for (int j = 0; j < 4; ++j)
        bf[j] = *(const bf16x8*)&Bs[(wc * 64 + j * 16 + lrow) * BK + lk];
#pragma unroll
      for (int i = 0; i < 4; ++i)
#pragma unroll
        for (int j = 0; j < 4; ++j)
          acc[i][j] = __builtin_amdgcn_mfma_f32_16x16x32_bf16(af[i], bf[j], acc[i][j], 0, 0, 0);
    }
  }

  // epilogue: C/D layout col = lane&15, row = (lane>>4)*4 + reg
  const int orow = row0 + wr * 64, ocol = col0 + wc * 64;
  const int lr = (lane >> 4) * 4;
#pragma unroll
  for (int i = 0; i < 4; ++i)
#pragma unroll
    for (int j = 0; j < 4; ++j) {
      const int cccol = ocol + j * 16 + lrow;
      const float bv = bias[cccol];
#pragma unroll
      for (int r = 0; r < 4; ++r) {
        const int rr = orow + i * 16 + lr + r;
        store_out(&C[(size_t)rr * N + cccol], acc[i][j][r] + bv);
      }
    }
}

// ============================================================================
// Gram partial: Spart[bh*8+p][i][j] = sum_{n in part p} q[n][i]*k[n][j]
// 1024 blocks (8 parts per bh) for occupancy; LDS-transpose staging,
// 3x3 MFMA tiles; 4-wave partial reduce in LDS aliased over staging buffers.
// ============================================================================
__global__ __launch_bounds__(256)
void gram_part(const u16* __restrict__ qkv, float* __restrict__ Spart) {
  __shared__ __align__(16) char smem[4 * 2 * 48 * 72 * 2];   // 55296 B
  const int blk = blockIdx.x, bh = blk >> 3, p = blk & 7;
  const int b = bh >> 3, h = bh & 7;
  const int t = threadIdx.x, wid = t >> 6, lane = t & 63;
  u16* qt = (u16*)smem + (size_t)(wid * 2 + 0) * (48 * 72);
  u16* kt = (u16*)smem + (size_t)(wid * 2 + 1) * (48 * 72);
  const int lrow = lane & 15, lk0 = (lane >> 4) * 8;

  f32x4 acc[3][3] = {};
#pragma unroll
  for (int cc = 0; cc < 2; ++cc) {
    const int n0 = (p * 8 + wid * 2 + cc) * 64;
    // stage q,k slices transposed: qt[i][nn] = qkv[b, n0+nn, h*48+i]
#pragma unroll
    for (int r = 0; r < 24; ++r) {
      const int e = r * 64 + lane;               // 0..1535
      const int nn = e / 24, i2 = e % 24;
      const size_t base = (size_t)(b * NN + n0 + nn) * (3 * CC) + h * DD + i2 * 2;
      const u32 qv = *(const u32*)(qkv + base);
      qt[(i2 * 2 + 0) * 72 + nn] = (u16)(qv & 0xffffu);
      qt[(i2 * 2 + 1) * 72 + nn] = (u16)(qv >> 16);
      const u32 kv = *(const u32*)(qkv + base + CC);
      kt[(i2 * 2 + 0) * 72 + nn] = (u16)(kv & 0xffffu);
      kt[(i2 * 2 + 1) * 72 + nn] = (u16)(kv >> 16);
    }
#pragma unroll
    for (int kk = 0; kk < 2; ++kk) {
      bf16x8 af[3], bf[3];
#pragma unroll
      for (int i = 0; i < 3; ++i)
        af[i] = *(const bf16x8*)&qt[(i * 16 + lrow) * 72 + kk * 32 + lk0];
#pragma unroll
      for (int j = 0; j < 3; ++j)
        bf[j] = *(const bf16x8*)&kt[(j * 16 + lrow) * 72 + kk * 32 + lk0];
#pragma unroll
      for (int i = 0; i < 3; ++i)
#pragma unroll
        for (int j = 0; j < 3; ++j)
          acc[i][j] = __builtin_amdgcn_mfma_f32_16x16x32_bf16(af[i], bf[j], acc[i][j], 0, 0, 0);
    }
  }
  __syncthreads();                  // staging buffers dead; alias partial-S
  float* Sp = (float*)smem;         // [4][48*48] f32 = 36864 B
  const int lr = (lane >> 4) * 4;
#pragma unroll
  for (int i = 0; i < 3; ++i)
#pragma unroll
    for (int j = 0; j < 3; ++j)
#pragma unroll
      for (int r = 0; r < 4; ++r)
        Sp[wid * 2304 + (i * 16 + lr + r) * 48 + (j * 16 + lrow)] = acc[i][j][r];
  __syncthreads();
  float* dst = Spart + (size_t)blk * 2304;
  for (int e = t; e < 2304; e += 256)
    dst[e] = Sp[e] + Sp[2304 + e] + Sp[4608 + e] + Sp[6912 + e];
}

// ============================================================================
// Reduce 8 partials + softmax over j.  128 blocks x 64 threads (48 active).
// ============================================================================
__global__ __launch_bounds__(64)
void softmax48(const float* __restrict__ Spart, float* __restrict__ attn) {
  const int bh = blockIdx.x;
  const int t = threadIdx.x;
  if (t >= 48) return;
  float row[48];
  float mx = -1e30f;
#pragma unroll
  for (int j = 0; j < 48; ++j) {
    float s = 0.f;
#pragma unroll
    for (int p = 0; p < 8; ++p)
      s += Spart[((size_t)(bh * 8 + p)) * 2304 + t * 48 + j];
    s *= 0.015625f;                 // N^-0.5 = 4096^-0.5
    row[j] = s;
    mx = fmaxf(mx, s);
  }
  float sum = 0.f;
#pragma unroll
  for (int j = 0; j < 48; ++j) {
    const float e = __expf(row[j] - mx);
    row[j] = e;
    sum += e;
  }
  const float inv = 1.f / sum;
#pragma unroll
  for (int j = 0; j < 48; ++j)
    attn[((size_t)bh * 48 + t) * 48 + j] = row[j] * inv;
}

// ============================================================================
// PV: R[b,i,h,n] = sum_j attn[bh][i][j] * v[b,n,j]
// ============================================================================
__global__ __launch_bounds__(256)
void pv_kernel(const u16* __restrict__ qkv, const float* __restrict__ attn,
               u16* __restrict__ R) {
  const int blk = blockIdx.x;            // 128 * 64
  const int bh = blk >> 6, nc = blk & 63;
  const int b = bh >> 3, h = bh & 7;
  const int t = threadIdx.x, wid = t >> 6, lane = t & 63;

  __shared__ __align__(16) u16 Albs[48 * 72];
  __shared__ __align__(16) u16 Vlds[64 * 72];

#pragma unroll
  for (int r = 0; r < 12; ++r) {
    const int e = r * 256 + t;          // 48 x 64
    const int i = e >> 6, j = e & 63;
    const float a = (j < 48) ? attn[((size_t)bh * 48 + i) * 48 + j] : 0.0f;
    Albs[i * 72 + j] = f2bf(a);
  }
  const int n0 = nc * 64;
#pragma unroll
  for (int r = 0; r < 16; ++r) {
    const int e = r * 256 + t;          // 64 x 64
    const int nn = e >> 6, j = e & 63;
    u16 v = 0;
    if (j < 48) v = qkv[(size_t)(b * NN + n0 + nn) * (3 * CC) + 2 * CC + h * DD + j];
    Vlds[nn * 72 + j] = v;
  }
  __syncthreads();

  const int lrow = lane & 15, lk0 = (lane >> 4) * 8;
  f32x4 acc[3] = {};
#pragma unroll
  for (int kk = 0; kk < 2; ++kk) {
    const bf16x8 bfrag = *(const bf16x8*)&Vlds[(wid * 16 + lrow) * 72 + kk * 32 + lk0];
#pragma unroll
    for (int i = 0; i < 3; ++i) {
      const bf16x8 afrag = *(const bf16x8*)&Albs[(i * 16 + lrow) * 72 + kk * 32 + lk0];
      acc[i] = __builtin_amdgcn_mfma_f32_16x16x32_bf16(afrag, bfrag, acc[i], 0, 0, 0);
    }
  }
  const int lr = (lane >> 4) * 4;
  const int n = n0 + wid * 16 + lrow;
#pragma unroll
  for (int i = 0; i < 3; ++i)
#pragma unroll
    for (int r = 0; r < 4; ++r) {
      const int ii = i * 16 + lr + r;
      R[(((size_t)b * DD + ii) * HH + h) * NN + n] = f2bf(acc[i][r]);
    }
}

// ============================================================================
extern "C" void kernel_launch(void* const* d_in, const int* in_sizes, int n_in,
                              void* d_out, int out_size, void* d_ws, size_t ws_size,
                              hipStream_t stream) {
  const float* x      = (const float*)d_in[0];
  const float* conv_w = (const float*)d_in[1];
  const float* conv_b = (const float*)d_in[2];
  const float* wq     = (const float*)d_in[3];
  const float* bq     = (const float*)d_in[4];
  const float* wkv    = (const float*)d_in[5];
  const float* bkv    = (const float*)d_in[6];
  const float* wp     = (const float*)d_in[7];
  const float* bp     = (const float*)d_in[8];
  float* y = (float*)d_out;

  char* ws = (char*)d_ws;
  u16*   Wf   = (u16*)ws;                               //    884,736 B
  float* bf_  = (float*)(ws + 884736);                  //      4,608 B
  u16*   wpb  = (u16*)(ws + 889344);                    //    294,912 B
  float* attn = (float*)(ws + 1184256);                 //  1,179,648 B
  u16*   qkv  = (u16*)(ws + 2363904);                   // 150,994,944 B
  char*  X    = ws + 153358848;                         //  50,331,648 B (time-shared)
  u16*   xb    = (u16*)X;      // phase 1: x in bf16
  float* Spart = (float*)X;    // phase 2: gram partials (9.4 MB)
  u16*   R     = (u16*)X;      // phase 3: PV output
  // total ws use: 203,690,496 B

  // independent precomputes
  f32_to_bf16<<<dim3((BB * NN * CC) / 8 / 256), dim3(256), 0, stream>>>(
      x, xb, (BB * NN * CC) / 8);
  f32_to_bf16<<<dim3((CC * CC) / 8 / 256), dim3(256), 0, stream>>>(
      wp, wpb, (CC * CC) / 8);
  fuse_weights<<<dim3(72), dim3(CC), 0, stream>>>(conv_w, conv_b, wq, bq,
                                                  wkv, bkv, Wf, bf_);
  // qkv = xb @ Wf^T + bf : M=65536, N=1152, K=384
  gemm_bt16<u16><<<dim3(9, 512), dim3(256), 0, stream>>>(
      xb, Wf, bf_, qkv, BB * NN, 3 * CC, CC);
  gram_part<<<dim3(BB * HH * 8), dim3(256), 0, stream>>>(qkv, Spart);
  softmax48<<<dim3(BB * HH), dim3(64), 0, stream>>>(Spart, attn);
  pv_kernel<<<dim3(BB * HH * (NN / 64)), dim3(256), 0, stream>>>(qkv, attn, R);
  // y = R @ wpb^T + bp : M=65536, N=384, K=384
  gemm_bt16<float><<<dim3(3, 512), dim3(256), 0, stream>>>(
      R, wpb, bp, y, BB * NN, CC, CC);
}

// Round 3
// 351.318 us; speedup vs baseline: 1.0550x; 1.0550x over previous
//
#include <hip/hip_runtime.h>
#include <hip/hip_bf16.h>
#include <stdint.h>

#define DEVI static __device__ __forceinline__

typedef __attribute__((ext_vector_type(4))) float f32x4;
typedef __attribute__((ext_vector_type(8))) short bf16x8;
typedef unsigned short u16;
typedef unsigned int u32;

// B=16, N=4096, C=384, H=8, D=48
#define BB 16
#define NN 4096
#define CC 384
#define HH 8
#define DD 48

DEVI u16 f2bf(float f) {
  union { float f; u32 u; } c; c.f = f;
  u32 u = c.u;
  u32 r = (u + 0x7FFFu + ((u >> 16) & 1u)) >> 16;
  return (u16)r;
}

DEVI void stage8(u16* dst, const float* src) {
  const f32x4 a = *(const f32x4*)(src);
  const f32x4 b = *(const f32x4*)(src + 4);
  union { bf16x8 v; u16 u[8]; } o;
  o.u[0] = f2bf(a[0]); o.u[1] = f2bf(a[1]); o.u[2] = f2bf(a[2]); o.u[3] = f2bf(a[3]);
  o.u[4] = f2bf(b[0]); o.u[5] = f2bf(b[1]); o.u[6] = f2bf(b[2]); o.u[7] = f2bf(b[3]);
  *(bf16x8*)dst = o.v;
}
DEVI void store_out(float* p, float v) { *p = v; }
DEVI void store_out(u16* p, float v) { *p = f2bf(v); }

// async global->LDS, 16B per lane. LDS dest must be linear: base + lane*16.
typedef const __attribute__((address_space(1))) void* gas_ptr;
typedef __attribute__((address_space(3))) void* las_ptr;
DEVI void gload16(const void* g, void* l) {
  __builtin_amdgcn_global_load_lds((gas_ptr)g, (las_ptr)l, 16, 0, 0);
}

// ============================================================================
// fp32 -> bf16 bulk convert (x and wp)
// ============================================================================
__global__ __launch_bounds__(256)
void f32_to_bf16(const float* __restrict__ in, u16* __restrict__ out, int n8) {
  const int i = blockIdx.x * 256 + threadIdx.x;
  if (i >= n8) return;
  stage8(out + (size_t)i * 8, in + (size_t)i * 8);
}

// ============================================================================
// Fused-weight precompute: W'[o][c] = sum_m wtop[o][m]*cw[m][c]
//                          b'[o]    = btop[o] + sum_m wtop[o][m]*cb[m]
// grid (72 o-blocks x 3 c-slices) x 128 threads = 216 blocks (was 72).
// ============================================================================
__global__ __launch_bounds__(128)
void fuse_weights(const float* __restrict__ cw, const float* __restrict__ cb,
                  const float* __restrict__ wq, const float* __restrict__ bq,
                  const float* __restrict__ wkv, const float* __restrict__ bkv,
                  u16* __restrict__ Wf, float* __restrict__ bf_) {
  const int o0 = blockIdx.x * 16;           // side-uniform (384%16==0)
  const int c = blockIdx.y * 128 + threadIdx.x;
  const float* wbase;
  const float* btop;
  if (o0 < CC) { wbase = wq + (size_t)o0 * CC;        btop = bq + o0; }
  else         { wbase = wkv + (size_t)(o0 - CC) * CC; btop = bkv + (o0 - CC); }
  float acc[16] = {};
  for (int m = 0; m < CC; ++m) {
    const float v = cw[(size_t)m * CC + c];
#pragma unroll
    for (int oo = 0; oo < 16; ++oo) acc[oo] += wbase[oo * CC + m] * v;
  }
#pragma unroll
  for (int oo = 0; oo < 16; ++oo) Wf[(size_t)(o0 + oo) * CC + c] = f2bf(acc[oo]);
  if (blockIdx.y == 0 && threadIdx.x < 16) {
    float s = btop[threadIdx.x];
    for (int m = 0; m < CC; ++m) s += wbase[threadIdx.x * CC + m] * cb[m];
    bf_[o0 + threadIdx.x] = s;
  }
}

// ============================================================================
// GEMM: C[M,N] = A[M,K] @ W[N,K]^T + bias[N]   (bf16 in, fp32 accumulate)
// BM=BN=128, BK=64; 4 waves (2x2) each own 64x64.
// T3-min pipeline: double-buffered LDS, next-tile global_load_lds issued
// BEFORE current tile's ds_read+MFMA, single syncthreads (vmcnt0+barrier)
// per tile -> HBM latency hides under compute.
// T2 swizzle both-sides (rule #21): linear LDS dest, inverse-swizzled global
// SOURCE column, XOR'd ds_read -> 16-way bank conflict eliminated.
// bf16 output: vectorized epilogue via LDS restage (16B stores).
// ============================================================================
template<typename OT>
__global__ __launch_bounds__(256)
void gemm_bt16(const u16* __restrict__ A, const u16* __restrict__ W,
               const float* __restrict__ bias, OT* __restrict__ C,
               int M, int N, int K) {
  constexpr int BM = 128, BN = 128, BK = 64;
  __shared__ __align__(16) u16 smem[32768];   // 64 KB: 2 x (As 8192 | Bs 8192)

  const int bn = blockIdx.x, bm = blockIdx.y;   // bn fastest -> A-tile L2/L3 reuse
  const int t = threadIdx.x;
  const int wid = t >> 6, lane = t & 63;
  const int wr = wid >> 1, wc = wid & 1;
  const int row0 = bm * BM, col0 = bn * BN;
  const int lrow = lane & 15;
  const int lswz = (lane & 7) << 3;             // ds_read XOR (row&7 == lane&7)

  // staging: thread t writes LDS linear bytes [t*16, +16) (+4096B per it).
  // linear pos = (row = it*32 + (t>>3), colbytes (t&7)*16). Content for a
  // swizzled read must come from logical col ^ ((row&7)<<4):
  const int arow = t >> 3;
  const int scol = ((t & 7) ^ ((t >> 3) & 7)) * 8;   // u16 units, it-invariant
  const u16* Ag = A + (size_t)(row0 + arow) * K + scol;
  const u16* Wg = W + (size_t)(col0 + arow) * K + scol;

  f32x4 acc[4][4] = {};
  const int NT = K / BK;

  auto stage = [&](int buf, int kt) {
    u16* Al = smem + buf * 16384 + t * 8;
    u16* Bl = smem + buf * 16384 + 8192 + t * 8;
    const int k0 = kt * BK;
#pragma unroll
    for (int it = 0; it < 4; ++it) {
      gload16(Ag + (size_t)(it * 32) * K + k0, Al + it * 2048);
      gload16(Wg + (size_t)(it * 32) * K + k0, Bl + it * 2048);
    }
  };

  stage(0, 0);
  __syncthreads();                 // drain tile 0
  int cur = 0;
  for (int kt = 0; kt < NT; ++kt) {
    if (kt + 1 < NT) stage(cur ^ 1, kt + 1);     // issue-early (overlaps MFMA)
    const u16* As = smem + cur * 16384;
    const u16* Bs = smem + cur * 16384 + 8192;
#pragma unroll
    for (int kk = 0; kk < 2; ++kk) {
      const int lk = (kk * 32 + (lane >> 4) * 8) ^ lswz;
      bf16x8 af[4], bf[4];
#pragma unroll
      for (int i = 0; i < 4; ++i)
        af[i] = *(const bf16x8*)&As[(wr * 64 + i * 16 + lrow) * BK + lk];
#pragma unroll
      for (int j = 0; j < 4; ++j)
        bf[j] = *(const bf16x8*)&Bs[(wc * 64 + j * 16 + lrow) * BK + lk];
#pragma unroll
      for (int i = 0; i < 4; ++i)
#pragma unroll
        for (int j = 0; j < 4; ++j)
          acc[i][j] = __builtin_amdgcn_mfma_f32_16x16x32_bf16(af[i], bf[j], acc[i][j], 0, 0, 0);
    }
    __syncthreads();               // wait-late: drains next tile's loads + LDS reads
    cur ^= 1;
  }

  // epilogue: C/D layout col = lane&15, row = (lane>>4)*4 + reg
  const int lr = (lane >> 4) * 4;
  if constexpr (sizeof(OT) == 2) {
    // restage tile as bf16 in LDS, then 16B vector stores (coalesced)
    u16* Ct = smem;                // [128][132] = 33792 B (pad 4: conflict-light)
#pragma unroll
    for (int i = 0; i < 4; ++i)
#pragma unroll
      for (int j = 0; j < 4; ++j) {
        const int ccol = wc * 64 + j * 16 + lrow;
        const float bv = bias[col0 + ccol];
#pragma unroll
        for (int r = 0; r < 4; ++r)
          Ct[(wr * 64 + i * 16 + lr + r) * 132 + ccol] = f2bf(acc[i][j][r] + bv);
      }
    __syncthreads();
#pragma unroll
    for (int it = 0; it < 8; ++it) {
      const int id = it * 256 + t;           // 2048 chunks of 8 u16
      const int row = id >> 4, c16 = (id & 15) * 8;
      *(bf16x8*)((u16*)C + (size_t)(row0 + row) * N + col0 + c16) =
          *(const bf16x8*)&Ct[row * 132 + c16];
    }
  } else {
    const int orow = row0 + wr * 64, ocol = col0 + wc * 64;
#pragma unroll
    for (int i = 0; i < 4; ++i)
#pragma unroll
      for (int j = 0; j < 4; ++j) {
        const int cc2 = ocol + j * 16 + lrow;
        const float bv = bias[cc2];
#pragma unroll
        for (int r = 0; r < 4; ++r)
          store_out(&C[(size_t)(orow + i * 16 + lr + r) * N + cc2], acc[i][j][r] + bv);
      }
  }
}

// ============================================================================
// Gram partial: Spart[bh*8+p][i][j] = sum_{n in part p} q[n][i]*k[n][j]
// 1024 blocks; LDS-transpose staging, 3x3 MFMA tiles; 4-wave reduce in LDS.
// ============================================================================
__global__ __launch_bounds__(256)
void gram_part(const u16* __restrict__ qkv, float* __restrict__ Spart) {
  __shared__ __align__(16) char smem[4 * 2 * 48 * 72 * 2];   // 55296 B
  const int blk = blockIdx.x, bh = blk >> 3, p = blk & 7;
  const int b = bh >> 3, h = bh & 7;
  const int t = threadIdx.x, wid = t >> 6, lane = t & 63;
  u16* qt = (u16*)smem + (size_t)(wid * 2 + 0) * (48 * 72);
  u16* kt = (u16*)smem + (size_t)(wid * 2 + 1) * (48 * 72);
  const int lrow = lane & 15, lk0 = (lane >> 4) * 8;

  f32x4 acc[3][3] = {};
#pragma unroll
  for (int cc = 0; cc < 2; ++cc) {
    const int n0 = (p * 8 + wid * 2 + cc) * 64;
#pragma unroll
    for (int r = 0; r < 24; ++r) {
      const int e = r * 64 + lane;               // 0..1535
      const int nn = e / 24, i2 = e % 24;
      const size_t base = (size_t)(b * NN + n0 + nn) * (3 * CC) + h * DD + i2 * 2;
      const u32 qv = *(const u32*)(qkv + base);
      qt[(i2 * 2 + 0) * 72 + nn] = (u16)(qv & 0xffffu);
      qt[(i2 * 2 + 1) * 72 + nn] = (u16)(qv >> 16);
      const u32 kv = *(const u32*)(qkv + base + CC);
      kt[(i2 * 2 + 0) * 72 + nn] = (u16)(kv & 0xffffu);
      kt[(i2 * 2 + 1) * 72 + nn] = (u16)(kv >> 16);
    }
#pragma unroll
    for (int kk = 0; kk < 2; ++kk) {
      bf16x8 af[3], bf[3];
#pragma unroll
      for (int i = 0; i < 3; ++i)
        af[i] = *(const bf16x8*)&qt[(i * 16 + lrow) * 72 + kk * 32 + lk0];
#pragma unroll
      for (int j = 0; j < 3; ++j)
        bf[j] = *(const bf16x8*)&kt[(j * 16 + lrow) * 72 + kk * 32 + lk0];
#pragma unroll
      for (int i = 0; i < 3; ++i)
#pragma unroll
        for (int j = 0; j < 3; ++j)
          acc[i][j] = __builtin_amdgcn_mfma_f32_16x16x32_bf16(af[i], bf[j], acc[i][j], 0, 0, 0);
    }
  }
  __syncthreads();                  // staging buffers dead; alias partial-S
  float* Sp = (float*)smem;         // [4][48*48] f32 = 36864 B
  const int lr = (lane >> 4) * 4;
#pragma unroll
  for (int i = 0; i < 3; ++i)
#pragma unroll
    for (int j = 0; j < 3; ++j)
#pragma unroll
      for (int r = 0; r < 4; ++r)
        Sp[wid * 2304 + (i * 16 + lr + r) * 48 + (j * 16 + lrow)] = acc[i][j][r];
  __syncthreads();
  float* dst = Spart + (size_t)blk * 2304;
  for (int e = t; e < 2304; e += 256)
    dst[e] = Sp[e] + Sp[2304 + e] + Sp[4608 + e] + Sp[6912 + e];
}

// ============================================================================
// Reduce 8 partials + softmax over j.  128 blocks x 64 threads (48 active).
// ============================================================================
__global__ __launch_bounds__(64)
void softmax48(const float* __restrict__ Spart, float* __restrict__ attn) {
  const int bh = blockIdx.x;
  const int t = threadIdx.x;
  if (t >= 48) return;
  float row[48];
  float mx = -1e30f;
#pragma unroll
  for (int j = 0; j < 48; ++j) {
    float s = 0.f;
#pragma unroll
    for (int p = 0; p < 8; ++p)
      s += Spart[((size_t)(bh * 8 + p)) * 2304 + t * 48 + j];
    s *= 0.015625f;                 // N^-0.5 = 4096^-0.5
    row[j] = s;
    mx = fmaxf(mx, s);
  }
  float sum = 0.f;
#pragma unroll
  for (int j = 0; j < 48; ++j) {
    const float e = __expf(row[j] - mx);
    row[j] = e;
    sum += e;
  }
  const float inv = 1.f / sum;
#pragma unroll
  for (int j = 0; j < 48; ++j)
    attn[((size_t)bh * 48 + t) * 48 + j] = row[j] * inv;
}

// ============================================================================
// PV: R[b,i,h,n] = sum_j attn[bh][i][j] * v[b,n,j]  (verbatim-torch R layout)
// ============================================================================
__global__ __launch_bounds__(256)
void pv_kernel(const u16* __restrict__ qkv, const float* __restrict__ attn,
               u16* __restrict__ R) {
  const int blk = blockIdx.x;            // 128 * 64
  const int bh = blk >> 6, nc = blk & 63;
  const int b = bh >> 3, h = bh & 7;
  const int t = threadIdx.x, wid = t >> 6, lane = t & 63;

  __shared__ __align__(16) u16 Albs[48 * 72];
  __shared__ __align__(16) u16 Vlds[64 * 72];

#pragma unroll
  for (int r = 0; r < 12; ++r) {
    const int e = r * 256 + t;          // 48 x 64
    const int i = e >> 6, j = e & 63;
    const float a = (j < 48) ? attn[((size_t)bh * 48 + i) * 48 + j] : 0.0f;
    Albs[i * 72 + j] = f2bf(a);
  }
  const int n0 = nc * 64;
#pragma unroll
  for (int r = 0; r < 16; ++r) {
    const int e = r * 256 + t;          // 64 x 64
    const int nn = e >> 6, j = e & 63;
    u16 v = 0;
    if (j < 48) v = qkv[(size_t)(b * NN + n0 + nn) * (3 * CC) + 2 * CC + h * DD + j];
    Vlds[nn * 72 + j] = v;
  }
  __syncthreads();

  const int lrow = lane & 15, lk0 = (lane >> 4) * 8;
  f32x4 acc[3] = {};
#pragma unroll
  for (int kk = 0; kk < 2; ++kk) {
    const bf16x8 bfrag = *(const bf16x8*)&Vlds[(wid * 16 + lrow) * 72 + kk * 32 + lk0];
#pragma unroll
    for (int i = 0; i < 3; ++i) {
      const bf16x8 afrag = *(const bf16x8*)&Albs[(i * 16 + lrow) * 72 + kk * 32 + lk0];
      acc[i] = __builtin_amdgcn_mfma_f32_16x16x32_bf16(afrag, bfrag, acc[i], 0, 0, 0);
    }
  }
  const int lr = (lane >> 4) * 4;
  const int n = n0 + wid * 16 + lrow;
#pragma unroll
  for (int i = 0; i < 3; ++i)
#pragma unroll
    for (int r = 0; r < 4; ++r) {
      const int ii = i * 16 + lr + r;
      R[(((size_t)b * DD + ii) * HH + h) * NN + n] = f2bf(acc[i][r]);
    }
}

// ============================================================================
extern "C" void kernel_launch(void* const* d_in, const int* in_sizes, int n_in,
                              void* d_out, int out_size, void* d_ws, size_t ws_size,
                              hipStream_t stream) {
  const float* x      = (const float*)d_in[0];
  const float* conv_w = (const float*)d_in[1];
  const float* conv_b = (const float*)d_in[2];
  const float* wq     = (const float*)d_in[3];
  const float* bq     = (const float*)d_in[4];
  const float* wkv    = (const float*)d_in[5];
  const float* bkv    = (const float*)d_in[6];
  const float* wp     = (const float*)d_in[7];
  const float* bp     = (const float*)d_in[8];
  float* y = (float*)d_out;

  char* ws = (char*)d_ws;
  u16*   Wf   = (u16*)ws;                               //    884,736 B
  float* bf_  = (float*)(ws + 884736);                  //      4,608 B
  u16*   wpb  = (u16*)(ws + 889344);                    //    294,912 B
  float* attn = (float*)(ws + 1184256);                 //  1,179,648 B
  u16*   qkv  = (u16*)(ws + 2363904);                   // 150,994,944 B
  char*  X    = ws + 153358848;                         //  50,331,648 B (time-shared)
  u16*   xb    = (u16*)X;      // phase 1: x in bf16 (dead after qkv GEMM)
  float* Spart = (float*)X;    // phase 2: gram partials (9.4 MB, dead after softmax)
  u16*   R     = (u16*)X;      // phase 3: PV output
  // total ws use: 203,690,496 B

  f32_to_bf16<<<dim3((BB * NN * CC) / 8 / 256), dim3(256), 0, stream>>>(
      x, xb, (BB * NN * CC) / 8);
  f32_to_bf16<<<dim3((CC * CC) / 8 / 256), dim3(256), 0, stream>>>(
      wp, wpb, (CC * CC) / 8);
  fuse_weights<<<dim3(72, 3), dim3(128), 0, stream>>>(conv_w, conv_b, wq, bq,
                                                      wkv, bkv, Wf, bf_);
  // qkv = xb @ Wf^T + bf : M=65536, N=1152, K=384
  gemm_bt16<u16><<<dim3(9, 512), dim3(256), 0, stream>>>(
      xb, Wf, bf_, qkv, BB * NN, 3 * CC, CC);
  gram_part<<<dim3(BB * HH * 8), dim3(256), 0, stream>>>(qkv, Spart);
  softmax48<<<dim3(BB * HH), dim3(64), 0, stream>>>(Spart, attn);
  pv_kernel<<<dim3(BB * HH * (NN / 64)), dim3(256), 0, stream>>>(qkv, attn, R);
  // y = R @ wpb^T + bp : M=65536, N=384, K=384
  gemm_bt16<float><<<dim3(3, 512), dim3(256), 0, stream>>>(
      R, wpb, bp, y, BB * NN, CC, CC);
}

// Round 4
// 288.628 us; speedup vs baseline: 1.2842x; 1.2172x over previous
//
#include <hip/hip_runtime.h>
#include <hip/hip_bf16.h>
#include <stdint.h>

#define DEVI static __device__ __forceinline__

typedef __attribute__((ext_vector_type(4))) float f32x4;
typedef __attribute__((ext_vector_type(8))) short bf16x8;
typedef unsigned short u16;
typedef unsigned int u32;
typedef unsigned long long u64;

// B=16, N=4096, C=384, H=8, D=48
#define BB 16
#define NN 4096
#define CC 384
#define HH 8
#define DD 48

DEVI u16 f2bf(float f) {
  union { float f; u32 u; } c; c.f = f;
  u32 u = c.u;
  u32 r = (u + 0x7FFFu + ((u >> 16) & 1u)) >> 16;
  return (u16)r;
}
DEVI float bf2f(u16 h) {
  union { float f; u32 u; } c; c.u = ((u32)h) << 16;
  return c.f;
}
DEVI void stage8(u16* dst, const float* src) {
  const f32x4 a = *(const f32x4*)(src);
  const f32x4 b = *(const f32x4*)(src + 4);
  union { bf16x8 v; u16 u[8]; } o;
  o.u[0] = f2bf(a[0]); o.u[1] = f2bf(a[1]); o.u[2] = f2bf(a[2]); o.u[3] = f2bf(a[3]);
  o.u[4] = f2bf(b[0]); o.u[5] = f2bf(b[1]); o.u[6] = f2bf(b[2]); o.u[7] = f2bf(b[3]);
  *(bf16x8*)dst = o.v;
}

typedef const __attribute__((address_space(1))) void* gas_ptr;
typedef __attribute__((address_space(3))) void* las_ptr;
DEVI void gload16(const void* g, void* l) {
  __builtin_amdgcn_global_load_lds((gas_ptr)g, (las_ptr)l, 16, 0, 0);
}

// ============================================================================
// fp32 -> bf16 bulk convert (wp)
// ============================================================================
__global__ __launch_bounds__(256)
void f32_to_bf16(const float* __restrict__ in, u16* __restrict__ out, int n8) {
  const int i = blockIdx.x * 256 + threadIdx.x;
  if (i >= n8) return;
  u16 tmp[8];
  stage8(tmp, in + (size_t)i * 8);
  *(bf16x8*)(out + (size_t)i * 8) = *(bf16x8*)tmp;
}

// ============================================================================
// x (f32 [B,N,C]) -> xb bf16 [B,N,C]  AND  xbT bf16 [B,C,N]  (fused transpose)
// 64x64 tiles via LDS.
// ============================================================================
__global__ __launch_bounds__(256)
void convert_x(const float* __restrict__ x, u16* __restrict__ xb,
               u16* __restrict__ xbT) {
  __shared__ __align__(8) u16 Lt[64 * 68];
  const int ct = blockIdx.x, nt = blockIdx.y, b = blockIdx.z;
  const int t = threadIdx.x;
  const int n0 = nt * 64, c0 = ct * 64;
#pragma unroll
  for (int it = 0; it < 4; ++it) {
    const int row = it * 16 + (t >> 4), col = (t & 15) * 4;
    const f32x4 v = *(const f32x4*)&x[((size_t)(b * NN + n0 + row)) * CC + c0 + col];
    u64 pk = (u64)f2bf(v[0]) | ((u64)f2bf(v[1]) << 16) |
             ((u64)f2bf(v[2]) << 32) | ((u64)f2bf(v[3]) << 48);
    *(u64*)(&Lt[row * 68 + col]) = pk;
  }
  __syncthreads();
#pragma unroll
  for (int it = 0; it < 2; ++it) {      // write xb (row-major)
    const int v = it * 256 + t, row = v >> 3, cg = v & 7;
    union { bf16x8 o; u64 q[2]; } u;
    u.q[0] = *(const u64*)(&Lt[row * 68 + cg * 8]);
    u.q[1] = *(const u64*)(&Lt[row * 68 + cg * 8 + 4]);
    *(bf16x8*)&xb[((size_t)(b * NN + n0 + row)) * CC + c0 + cg * 8] = u.o;
  }
#pragma unroll
  for (int it = 0; it < 2; ++it) {      // write xbT (transposed)
    const int v = it * 256 + t, c = v >> 3, ng = v & 7;
    union { bf16x8 o; u16 e[8]; } u;
#pragma unroll
    for (int r = 0; r < 8; ++r) u.e[r] = Lt[(ng * 8 + r) * 68 + c];
    *(bf16x8*)&xbT[((size_t)(b * CC + c0 + c)) * NN + n0 + ng * 8] = u.o;
  }
}

// ============================================================================
// Fused weights: Wf[o][c] = sum_m wtop[o][m]*cw[m][c]; bf_[o] = b + w@cb
// o<384: wq | 384..768: wkv-k | 768..1152: wkv-v. Also UvT[c][j]=Wf[768+j][c].
// ============================================================================
__global__ __launch_bounds__(128)
void fuse_weights(const float* __restrict__ cw, const float* __restrict__ cb,
                  const float* __restrict__ wq, const float* __restrict__ bq,
                  const float* __restrict__ wkv, const float* __restrict__ bkv,
                  u16* __restrict__ Wf, u16* __restrict__ UvT,
                  float* __restrict__ bf_) {
  const int o0 = blockIdx.x * 16;
  const int c = blockIdx.y * 128 + threadIdx.x;
  const float* wbase;
  const float* btop;
  if (o0 < CC) { wbase = wq + (size_t)o0 * CC;        btop = bq + o0; }
  else         { wbase = wkv + (size_t)(o0 - CC) * CC; btop = bkv + (o0 - CC); }
  float acc[16] = {};
  for (int m = 0; m < CC; ++m) {
    const float v = cw[(size_t)m * CC + c];
#pragma unroll
    for (int oo = 0; oo < 16; ++oo) acc[oo] += wbase[oo * CC + m] * v;
  }
#pragma unroll
  for (int oo = 0; oo < 16; ++oo) {
    const u16 bv = f2bf(acc[oo]);
    Wf[(size_t)(o0 + oo) * CC + c] = bv;
    if (o0 >= 2 * CC) UvT[(size_t)c * CC + (o0 - 2 * CC + oo)] = bv;
  }
  if (blockIdx.y == 0 && threadIdx.x < 16) {
    float s = btop[threadIdx.x];
    for (int m = 0; m < CC; ++m) s += wbase[threadIdx.x * CC + m] * cb[m];
    bf_[o0 + threadIdx.x] = s;
  }
}

// ============================================================================
// colsum: sx[b][c] = sum_n xbT[b][c][n]
// ============================================================================
__global__ __launch_bounds__(256)
void colsum(const u16* __restrict__ xbT, float* __restrict__ sx) {
  const int b = blockIdx.y, c = blockIdx.x * 16 + (threadIdx.x >> 4);
  const int sl = threadIdx.x & 15;
  const u16* src = xbT + ((size_t)(b * CC + c)) * NN + sl * 256;
  float s = 0.f;
  for (int i = 0; i < 32; ++i) {
    const bf16x8 v = *(const bf16x8*)(src + i * 8);
#pragma unroll
    for (int r = 0; r < 8; ++r) s += bf2f((u16)v[r]);
  }
#pragma unroll
  for (int m = 1; m < 16; m <<= 1) s += __shfl_xor(s, m, 64);
  if (sl == 0) sx[b * CC + c] = s;
}

// ============================================================================
// proj_sx: P[b][o] = sum_c Wf[o][c] * sx[b][c], o<768
// ============================================================================
__global__ __launch_bounds__(128)
void proj_sx(const u16* __restrict__ Wf, const float* __restrict__ sx,
             float* __restrict__ P) {
  __shared__ float sl[CC];
  const int b = blockIdx.y, o = blockIdx.x * 128 + threadIdx.x;
  for (int i = threadIdx.x; i < CC; i += 128) sl[i] = sx[b * CC + i];
  __syncthreads();
  float acc = 0.f;
  const u16* wr = Wf + (size_t)o * CC;
  for (int c8 = 0; c8 < CC; c8 += 8) {
    const bf16x8 w = *(const bf16x8*)(wr + c8);
#pragma unroll
    for (int r = 0; r < 8; ++r) acc += bf2f((u16)w[r]) * sl[c8 + r];
  }
  P[b * 768 + o] = acc;
}

// ============================================================================
// Generic GEMM: C[M,N](+p partials) = A[M,K-slice] @ W[N,K-slice]^T (+bias)
// bf16 in, fp32 acc. 128x128 tile, BK=64 dbuf, global_load_lds w=16, T2
// both-sides swizzle, flat grid + bijective XCD swizzle, optional batching.
// BIASMODE: 0 none, 1 per-col, 2 per-row.
// ============================================================================
template<typename OT, int BIASMODE>
__global__ __launch_bounds__(256)
void gemm_f(const u16* __restrict__ A, const u16* __restrict__ W,
            const float* __restrict__ bias, OT* __restrict__ C,
            int M, int N, int K, int klen, int nbn, int nbm, int tpb,
            long sA, long sW, long sC, long sCp, long sBias) {
  constexpr int BK = 64;
  __shared__ __align__(16) u16 smem[32768];   // 64 KB: 2 x (As 8192 | Bs 8192)

  const int nx = gridDim.x;
  const int lin = blockIdx.x;
  const int lin2 = (lin & 7) * (nx >> 3) + (lin >> 3);   // XCD swizzle (nx%8==0)
  const int b = lin2 / tpb;
  int t2 = lin2 % tpb;
  const int bn = t2 % nbn; t2 /= nbn;
  const int bm = t2 % nbm;
  const int p = t2 / nbm;
  A += (size_t)b * sA; W += (size_t)b * sW;
  C += (size_t)b * sC + (size_t)p * sCp;
  if (BIASMODE) bias += (size_t)b * sBias;

  const int t = threadIdx.x;
  const int wid = t >> 6, lane = t & 63;
  const int wr = wid >> 1, wc = wid & 1;
  const int row0 = bm * 128, col0 = bn * 128;
  const int lrow = lane & 15;
  const int lswz = (lane & 7) << 3;
  const int kstart = p * klen;

  const int arow = t >> 3;
  const int scol = ((t & 7) ^ ((t >> 3) & 7)) * 8;
  const u16* Ag = A + (size_t)(row0 + arow) * K + scol;
  const u16* Wg = W + (size_t)(col0 + arow) * K + scol;

  f32x4 acc[4][4] = {};
  const int NT = klen >> 6;

  auto stage = [&](int buf, int kt) {
    u16* Al = smem + buf * 16384 + t * 8;
    u16* Bl = smem + buf * 16384 + 8192 + t * 8;
    const int k0 = kstart + kt * BK;
#pragma unroll
    for (int it = 0; it < 4; ++it) {
      gload16(Ag + (size_t)(it * 32) * K + k0, Al + it * 2048);
      gload16(Wg + (size_t)(it * 32) * K + k0, Bl + it * 2048);
    }
  };

  stage(0, 0);
  __syncthreads();
  int cur = 0;
  for (int kt = 0; kt < NT; ++kt) {
    if (kt + 1 < NT) stage(cur ^ 1, kt + 1);
    const u16* As = smem + cur * 16384;
    const u16* Bs = smem + cur * 16384 + 8192;
#pragma unroll
    for (int kk = 0; kk < 2; ++kk) {
      const int lk = (kk * 32 + (lane >> 4) * 8) ^ lswz;
      bf16x8 af[4], bf[4];
#pragma unroll
      for (int i = 0; i < 4; ++i)
        af[i] = *(const bf16x8*)&As[(wr * 64 + i * 16 + lrow) * BK + lk];
#pragma unroll
      for (int j = 0; j < 4; ++j)
        bf[j] = *(const bf16x8*)&Bs[(wc * 64 + j * 16 + lrow) * BK + lk];
#pragma unroll
      for (int i = 0; i < 4; ++i)
#pragma unroll
        for (int j = 0; j < 4; ++j)
          acc[i][j] = __builtin_amdgcn_mfma_f32_16x16x32_bf16(af[i], bf[j], acc[i][j], 0, 0, 0);
    }
    __syncthreads();
    cur ^= 1;
  }

  const int lr = (lane >> 4) * 4;
  if constexpr (sizeof(OT) == 2) {
    u16* Ct = smem;                 // [128][132]
#pragma unroll
    for (int i = 0; i < 4; ++i)
#pragma unroll
      for (int j = 0; j < 4; ++j) {
        const int ccol = wc * 64 + j * 16 + lrow;
        float bv = 0.f;
        if constexpr (BIASMODE == 1) bv = bias[col0 + ccol];
#pragma unroll
        for (int r = 0; r < 4; ++r) {
          const int rrow = wr * 64 + i * 16 + lr + r;
          float b2 = bv;
          if constexpr (BIASMODE == 2) b2 = bias[row0 + rrow];
          Ct[rrow * 132 + ccol] = f2bf(acc[i][j][r] + b2);
        }
      }
    __syncthreads();
#pragma unroll
    for (int it = 0; it < 8; ++it) {
      const int id = it * 256 + t;
      const int row = id >> 4, c16 = (id & 15) * 8;
      *(bf16x8*)((u16*)C + (size_t)(row0 + row) * N + col0 + c16) =
          *(const bf16x8*)&Ct[row * 132 + c16];
    }
  } else {
    const int orow = row0 + wr * 64, ocol = col0 + wc * 64;
#pragma unroll
    for (int i = 0; i < 4; ++i)
#pragma unroll
      for (int j = 0; j < 4; ++j) {
        const int cc2 = ocol + j * 16 + lrow;
        float bv = 0.f;
        if constexpr (BIASMODE == 1) bv = bias[cc2];
#pragma unroll
        for (int r = 0; r < 4; ++r) {
          const int rr = orow + i * 16 + lr + r;
          float b2 = bv;
          if constexpr (BIASMODE == 2) b2 = bias[rr];
          C[(size_t)rr * N + cc2] = acc[i][j][r] + b2;
        }
      }
  }
}

// ============================================================================
// reduceG: Gbf[b] = bf16( sum_p Gpart[b][p] )
// ============================================================================
__global__ __launch_bounds__(256)
void reduceG(const float* __restrict__ Gp, u16* __restrict__ Gbf) {
  const int b = blockIdx.y;
  const int e = blockIdx.x * 256 + threadIdx.x;
  const float* s = Gp + (size_t)b * 4 * 147456 + e;
  Gbf[(size_t)b * 147456 + e] =
      f2bf(s[0] + s[147456] + s[2 * 147456] + s[3 * 147456]);
}

// ============================================================================
// s_softmax: per (b,h):
//   S = M1_h @ Uk_h^T (+rank-1 bias terms), *N^-0.5, softmax ->
//   AU = attn @ Uv_h  (written to AUb[b] rows i*8+h), rbias = attn @ bv'
// ============================================================================
__global__ __launch_bounds__(256)
void s_softmax(const u16* __restrict__ M1g, const u16* __restrict__ Wf,
               const float* __restrict__ bf_, const float* __restrict__ P,
               const u16* __restrict__ UvT, u16* __restrict__ AUb,
               float* __restrict__ rbias) {
  __shared__ float Sf[48 * 52];
  __shared__ __align__(16) u16 att[48 * 56];
  const int bh = blockIdx.x, b = bh >> 3, h = bh & 7;
  const int t = threadIdx.x, wid = t >> 6, lane = t & 63;
  const int lrow = lane & 15, lkq = lane >> 4;

  // Phase A: waves 0..2 compute S rows [wid*16, +16), full K=384
  if (wid < 3) {
    f32x4 acc[3] = {};
    const u16* Arow = M1g + (size_t)b * 147456 + (size_t)(h * 48 + wid * 16 + lrow) * CC;
    const u16* Brow = Wf + (size_t)(CC + h * 48) * CC;    // Uk
    for (int ks = 0; ks < 12; ++ks) {
      const int k = ks * 32 + lkq * 8;
      const bf16x8 af = *(const bf16x8*)(Arow + k);
#pragma unroll
      for (int j = 0; j < 3; ++j) {
        const bf16x8 bfr = *(const bf16x8*)(Brow + (size_t)(j * 16 + lrow) * CC + k);
        acc[j] = __builtin_amdgcn_mfma_f32_16x16x32_bf16(af, bfr, acc[j], 0, 0, 0);
      }
    }
    const int lr = lkq * 4;
#pragma unroll
    for (int j = 0; j < 3; ++j)
#pragma unroll
      for (int r = 0; r < 4; ++r)
        Sf[(wid * 16 + lr + r) * 52 + j * 16 + lrow] = acc[j][r];
  }
  __syncthreads();

  // Phase B: softmax rows (t<48)
  if (t < 48) {
    const float bi = bf_[h * 48 + t];
    const float pq = P[b * 768 + h * 48 + t];
    float row[48];
    float mx = -1e30f;
#pragma unroll
    for (int j = 0; j < 48; ++j) {
      const float g = bf_[CC + h * 48 + j];
      const float pk = P[b * 768 + CC + h * 48 + j];
      const float s = (Sf[t * 52 + j] + bi * pk + pq * g + 4096.f * bi * g) * 0.015625f;
      row[j] = s;
      mx = fmaxf(mx, s);
    }
    float sum = 0.f;
#pragma unroll
    for (int j = 0; j < 48; ++j) { row[j] = __expf(row[j] - mx); sum += row[j]; }
    const float inv = 1.f / sum;
    float rb = 0.f;
#pragma unroll
    for (int j = 0; j < 48; ++j) {
      const float a = row[j] * inv;
      att[t * 56 + j] = f2bf(a);
      rb += a * bf_[2 * CC + h * 48 + j];
    }
#pragma unroll
    for (int j = 48; j < 56; ++j) att[t * 56 + j] = 0;
    rbias[b * CC + t * 8 + h] = rb;
  }
  __syncthreads();

  // Phase C: AU = attn @ Uv_h (K=64 zero-padded), 4 waves x 96 cols
  f32x4 acc[3][6] = {};
  const u16* Vbase = UvT + h * 48;
  const bf16x8 z = {};
#pragma unroll
  for (int kk = 0; kk < 2; ++kk) {
    const int k = kk * 32 + lkq * 8;
    bf16x8 af[3];
#pragma unroll
    for (int i = 0; i < 3; ++i) {
      af[i] = *(const bf16x8*)&att[(i * 16 + lrow) * 56 + k];
      if (k >= 48) af[i] = z;
    }
#pragma unroll
    for (int ct = 0; ct < 6; ++ct) {
      const int c = wid * 96 + ct * 16 + lrow;
      bf16x8 bfr = *(const bf16x8*)(Vbase + (size_t)c * CC + k);
      if (k >= 48) bfr = z;
#pragma unroll
      for (int i = 0; i < 3; ++i)
        acc[i][ct] = __builtin_amdgcn_mfma_f32_16x16x32_bf16(af[i], bfr, acc[i][ct], 0, 0, 0);
    }
  }
  const int lr = lkq * 4;
#pragma unroll
  for (int i = 0; i < 3; ++i)
#pragma unroll
    for (int ct = 0; ct < 6; ++ct) {
      const int c = wid * 96 + ct * 16 + lrow;
#pragma unroll
      for (int r = 0; r < 4; ++r) {
        const int ii = i * 16 + lr + r;
        AUb[(size_t)b * 147456 + (size_t)(ii * 8 + h) * CC + c] = f2bf(acc[i][ct][r]);
      }
    }
}

// ============================================================================
extern "C" void kernel_launch(void* const* d_in, const int* in_sizes, int n_in,
                              void* d_out, int out_size, void* d_ws, size_t ws_size,
                              hipStream_t stream) {
  const float* x      = (const float*)d_in[0];
  const float* conv_w = (const float*)d_in[1];
  const float* conv_b = (const float*)d_in[2];
  const float* wq     = (const float*)d_in[3];
  const float* bq     = (const float*)d_in[4];
  const float* wkv    = (const float*)d_in[5];
  const float* bkv    = (const float*)d_in[6];
  const float* wp     = (const float*)d_in[7];
  const float* bp     = (const float*)d_in[8];
  float* y = (float*)d_out;

  char* ws = (char*)d_ws;
  u16*   Wf    = (u16*)(ws + 0);              //   884,736
  float* bf_   = (float*)(ws + 884736);       //     4,608
  u16*   wpb   = (u16*)(ws + 889344);         //   294,912
  u16*   UvT   = (u16*)(ws + 1184256);        //   294,912
  float* sx    = (float*)(ws + 1479168);      //    24,576
  float* P     = (float*)(ws + 1503744);      //    49,152
  float* rb    = (float*)(ws + 1552896);      //    24,576
  u16*   M1g   = (u16*)(ws + 1577472);        // 4,718,592
  u16*   Gbf   = (u16*)(ws + 6296064);        // 4,718,592
  u16*   AUb   = (u16*)(ws + 11014656);       // 4,718,592
  float* Gpart = (float*)(ws + 15733248);     // 37,748,736
  u16*   xb    = (u16*)(ws + 53481984);       // 50,331,648
  u16*   xbT   = (u16*)(ws + 103813632);      // 50,331,648 (dead after gram)
  u16*   R     = xbT;                         // aliases xbT
  // total ws use: 154,145,280 B

  convert_x<<<dim3(6, 64, 16), dim3(256), 0, stream>>>(x, xb, xbT);
  f32_to_bf16<<<dim3(72), dim3(256), 0, stream>>>(wp, wpb, (CC * CC) / 8);
  fuse_weights<<<dim3(72, 3), dim3(128), 0, stream>>>(conv_w, conv_b, wq, bq,
                                                      wkv, bkv, Wf, UvT, bf_);
  colsum<<<dim3(24, 16), dim3(256), 0, stream>>>(xbT, sx);
  proj_sx<<<dim3(6, 16), dim3(128), 0, stream>>>(Wf, sx, P);
  // Gram partials: Gpart[b][p] = xbT[b][ti] @ xbT[b][tj]^T over k-slice p
  gemm_f<float, 0><<<dim3(576), dim3(256), 0, stream>>>(
      xbT, xbT, nullptr, Gpart, CC, CC, NN, 1024, 3, 3, 36,
      (long)CC * NN, (long)CC * NN, 4L * 147456, 147456, 0);
  reduceG<<<dim3(576, 16), dim3(256), 0, stream>>>(Gpart, Gbf);
  // M1g[b] = Uq @ Gx_b  (Gx symmetric)
  gemm_f<u16, 0><<<dim3(144), dim3(256), 0, stream>>>(
      Wf, Gbf, nullptr, M1g, CC, CC, CC, CC, 3, 3, 9,
      0, 147456, 147456, 0, 0);
  s_softmax<<<dim3(128), dim3(256), 0, stream>>>(M1g, Wf, bf_, P, UvT, AUb, rb);
  // R[b] = AUb[b] @ xb_b^T + rbias (row-bias), R rows = (i*8+h), cols = n
  gemm_f<u16, 2><<<dim3(1536), dim3(256), 0, stream>>>(
      AUb, xb, rb, R, CC, NN, CC, CC, 32, 3, 96,
      147456, (long)NN * CC, (long)NN * CC, 0, CC);
  // y = R @ wpb^T + bp
  gemm_f<float, 1><<<dim3(1536), dim3(256), 0, stream>>>(
      R, wpb, bp, y, BB * NN, CC, CC, CC, 3, 512, 1536,
      0, 0, 0, 0, 0);
}

// Round 5
// 260.796 us; speedup vs baseline: 1.4212x; 1.1067x over previous
//
#include <hip/hip_runtime.h>
#include <hip/hip_bf16.h>
#include <stdint.h>

#define DEVI static __device__ __forceinline__

typedef __attribute__((ext_vector_type(4))) float f32x4;
typedef __attribute__((ext_vector_type(8))) short bf16x8;
typedef unsigned short u16;
typedef unsigned int u32;
typedef unsigned long long u64;

// B=16, N=4096, C=384, H=8, D=48
#define BB 16
#define NN 4096
#define CC 384
#define HH 8
#define DD 48

DEVI u16 f2bf(float f) {
  union { float f; u32 u; } c; c.f = f;
  u32 u = c.u;
  u32 r = (u + 0x7FFFu + ((u >> 16) & 1u)) >> 16;
  return (u16)r;
}
DEVI float bf2f(u16 h) {
  union { float f; u32 u; } c; c.u = ((u32)h) << 16;
  return c.f;
}
DEVI void stage8(u16* dst, const float* src) {
  const f32x4 a = *(const f32x4*)(src);
  const f32x4 b = *(const f32x4*)(src + 4);
  union { bf16x8 v; u16 u[8]; } o;
  o.u[0] = f2bf(a[0]); o.u[1] = f2bf(a[1]); o.u[2] = f2bf(a[2]); o.u[3] = f2bf(a[3]);
  o.u[4] = f2bf(b[0]); o.u[5] = f2bf(b[1]); o.u[6] = f2bf(b[2]); o.u[7] = f2bf(b[3]);
  *(bf16x8*)dst = o.v;
}

typedef const __attribute__((address_space(1))) void* gas_ptr;
typedef __attribute__((address_space(3))) void* las_ptr;
DEVI void gload16(const void* g, void* l) {
  __builtin_amdgcn_global_load_lds((gas_ptr)g, (las_ptr)l, 16, 0, 0);
}

// ============================================================================
// fp32 -> bf16 bulk convert (wp)
// ============================================================================
__global__ __launch_bounds__(256)
void f32_to_bf16(const float* __restrict__ in, u16* __restrict__ out, int n8) {
  const int i = blockIdx.x * 256 + threadIdx.x;
  if (i >= n8) return;
  u16 tmp[8];
  stage8(tmp, in + (size_t)i * 8);
  *(bf16x8*)(out + (size_t)i * 8) = *(bf16x8*)tmp;
}

// ============================================================================
// x (f32 [B,N,C]) -> xb bf16 [B,N,C]  AND  xbT bf16 [B,C,N]  (fused transpose)
// ============================================================================
__global__ __launch_bounds__(256)
void convert_x(const float* __restrict__ x, u16* __restrict__ xb,
               u16* __restrict__ xbT) {
  __shared__ __align__(8) u16 Lt[64 * 68];
  const int ct = blockIdx.x, nt = blockIdx.y, b = blockIdx.z;
  const int t = threadIdx.x;
  const int n0 = nt * 64, c0 = ct * 64;
#pragma unroll
  for (int it = 0; it < 4; ++it) {
    const int row = it * 16 + (t >> 4), col = (t & 15) * 4;
    const f32x4 v = *(const f32x4*)&x[((size_t)(b * NN + n0 + row)) * CC + c0 + col];
    u64 pk = (u64)f2bf(v[0]) | ((u64)f2bf(v[1]) << 16) |
             ((u64)f2bf(v[2]) << 32) | ((u64)f2bf(v[3]) << 48);
    *(u64*)(&Lt[row * 68 + col]) = pk;
  }
  __syncthreads();
#pragma unroll
  for (int it = 0; it < 2; ++it) {      // write xb (row-major)
    const int v = it * 256 + t, row = v >> 3, cg = v & 7;
    union { bf16x8 o; u64 q[2]; } u;
    u.q[0] = *(const u64*)(&Lt[row * 68 + cg * 8]);
    u.q[1] = *(const u64*)(&Lt[row * 68 + cg * 8 + 4]);
    *(bf16x8*)&xb[((size_t)(b * NN + n0 + row)) * CC + c0 + cg * 8] = u.o;
  }
#pragma unroll
  for (int it = 0; it < 2; ++it) {      // write xbT (transposed)
    const int v = it * 256 + t, c = v >> 3, ng = v & 7;
    union { bf16x8 o; u16 e[8]; } u;
#pragma unroll
    for (int r = 0; r < 8; ++r) u.e[r] = Lt[(ng * 8 + r) * 68 + c];
    *(bf16x8*)&xbT[((size_t)(b * CC + c0 + c)) * NN + n0 + ng * 8] = u.o;
  }
}

// ============================================================================
// Fused weights (FIXED): stage the 16 wtop rows in LDS once (coalesced),
// inner loop = LDS broadcast + FMA. Was: serialized uniform scalar loads
// (102us, VALUBusy 2%).
// ============================================================================
__global__ __launch_bounds__(384)
void fuse_weights(const float* __restrict__ cw, const float* __restrict__ cb,
                  const float* __restrict__ wq, const float* __restrict__ bq,
                  const float* __restrict__ wkv, const float* __restrict__ bkv,
                  u16* __restrict__ Wf, u16* __restrict__ UvT,
                  float* __restrict__ bf_) {
  __shared__ float wl[16 * CC];              // 24 KB
  const int o0 = blockIdx.x * 16;            // 72 blocks
  const int t = threadIdx.x;                 // 384 threads: t == c
  const float* wbase;
  const float* btop;
  if (o0 < CC) { wbase = wq + (size_t)o0 * CC;        btop = bq + o0; }
  else         { wbase = wkv + (size_t)(o0 - CC) * CC; btop = bkv + (o0 - CC); }
  for (int i = t; i < 16 * CC; i += 384) wl[i] = wbase[i];
  __syncthreads();
  float acc[16] = {};
  for (int m = 0; m < CC; ++m) {
    const float v = cw[(size_t)m * CC + t];  // coalesced across threads
#pragma unroll
    for (int oo = 0; oo < 16; ++oo) acc[oo] += wl[oo * CC + m] * v;  // broadcast
  }
#pragma unroll
  for (int oo = 0; oo < 16; ++oo) {
    const u16 bv = f2bf(acc[oo]);
    Wf[(size_t)(o0 + oo) * CC + t] = bv;
    if (o0 >= 2 * CC) UvT[(size_t)t * CC + (o0 - 2 * CC + oo)] = bv;
  }
  if (t < 16) {
    float s = btop[t];
    for (int m = 0; m < CC; ++m) s += wl[t * CC + m] * cb[m];
    bf_[o0 + t] = s;
  }
}

// ============================================================================
// colsum: sx[b][c] = sum_n xbT[b][c][n]
// ============================================================================
__global__ __launch_bounds__(256)
void colsum(const u16* __restrict__ xbT, float* __restrict__ sx) {
  const int b = blockIdx.y, c = blockIdx.x * 16 + (threadIdx.x >> 4);
  const int sl = threadIdx.x & 15;
  const u16* src = xbT + ((size_t)(b * CC + c)) * NN + sl * 256;
  float s = 0.f;
  for (int i = 0; i < 32; ++i) {
    const bf16x8 v = *(const bf16x8*)(src + i * 8);
#pragma unroll
    for (int r = 0; r < 8; ++r) s += bf2f((u16)v[r]);
  }
#pragma unroll
  for (int m = 1; m < 16; m <<= 1) s += __shfl_xor(s, m, 64);
  if (sl == 0) sx[b * CC + c] = s;
}

// ============================================================================
// proj_sx: P[b][o] = sum_c Wf[o][c] * sx[b][c], o<768
// ============================================================================
__global__ __launch_bounds__(128)
void proj_sx(const u16* __restrict__ Wf, const float* __restrict__ sx,
             float* __restrict__ P) {
  __shared__ float sl[CC];
  const int b = blockIdx.y, o = blockIdx.x * 128 + threadIdx.x;
  for (int i = threadIdx.x; i < CC; i += 128) sl[i] = sx[b * CC + i];
  __syncthreads();
  float acc = 0.f;
  const u16* wr = Wf + (size_t)o * CC;
  for (int c8 = 0; c8 < CC; c8 += 8) {
    const bf16x8 w = *(const bf16x8*)(wr + c8);
#pragma unroll
    for (int r = 0; r < 8; ++r) acc += bf2f((u16)w[r]) * sl[c8 + r];
  }
  P[b * 768 + o] = acc;
}

// ============================================================================
// Generic GEMM: C[M,N](+p partials) = A[M,K-slice] @ W[N,K-slice]^T (+bias)
// TRI: symmetric output -- compute only 6 upper tiles of the 3x3 tiling.
// ============================================================================
template<typename OT, int BIASMODE, int TRI = 0>
__global__ __launch_bounds__(256)
void gemm_f(const u16* __restrict__ A, const u16* __restrict__ W,
            const float* __restrict__ bias, OT* __restrict__ C,
            int M, int N, int K, int klen, int nbn, int nbm, int tpb,
            long sA, long sW, long sC, long sCp, long sBias) {
  constexpr int BK = 64;
  __shared__ __align__(16) u16 smem[32768];   // 64 KB: 2 x (As 8192 | Bs 8192)

  const int nx = gridDim.x;
  const int lin = blockIdx.x;
  const int lin2 = (lin & 7) * (nx >> 3) + (lin >> 3);   // XCD swizzle (nx%8==0)
  const int b = lin2 / tpb;
  int t2 = lin2 % tpb;
  int bn, bm, p;
  if constexpr (TRI) {
    const int tl = t2 % 6; p = t2 / 6;
    bm = tl < 3 ? 0 : (tl < 5 ? 1 : 2);
    bn = tl < 3 ? tl : (tl < 5 ? tl - 2 : 2);
  } else {
    bn = t2 % nbn; t2 /= nbn;
    bm = t2 % nbm;
    p = t2 / nbm;
  }
  A += (size_t)b * sA; W += (size_t)b * sW;
  C += (size_t)b * sC + (size_t)p * sCp;
  if (BIASMODE) bias += (size_t)b * sBias;

  const int t = threadIdx.x;
  const int wid = t >> 6, lane = t & 63;
  const int wr = wid >> 1, wc = wid & 1;
  const int row0 = bm * 128, col0 = bn * 128;
  const int lrow = lane & 15;
  const int lswz = (lane & 7) << 3;
  const int kstart = p * klen;

  const int arow = t >> 3;
  const int scol = ((t & 7) ^ ((t >> 3) & 7)) * 8;
  const u16* Ag = A + (size_t)(row0 + arow) * K + scol;
  const u16* Wg = W + (size_t)(col0 + arow) * K + scol;

  f32x4 acc[4][4] = {};
  const int NT = klen >> 6;

  auto stage = [&](int buf, int kt) {
    u16* Al = smem + buf * 16384 + t * 8;
    u16* Bl = smem + buf * 16384 + 8192 + t * 8;
    const int k0 = kstart + kt * BK;
#pragma unroll
    for (int it = 0; it < 4; ++it) {
      gload16(Ag + (size_t)(it * 32) * K + k0, Al + it * 2048);
      gload16(Wg + (size_t)(it * 32) * K + k0, Bl + it * 2048);
    }
  };

  stage(0, 0);
  __syncthreads();
  int cur = 0;
  for (int kt = 0; kt < NT; ++kt) {
    if (kt + 1 < NT) stage(cur ^ 1, kt + 1);
    const u16* As = smem + cur * 16384;
    const u16* Bs = smem + cur * 16384 + 8192;
#pragma unroll
    for (int kk = 0; kk < 2; ++kk) {
      const int lk = (kk * 32 + (lane >> 4) * 8) ^ lswz;
      bf16x8 af[4], bf[4];
#pragma unroll
      for (int i = 0; i < 4; ++i)
        af[i] = *(const bf16x8*)&As[(wr * 64 + i * 16 + lrow) * BK + lk];
#pragma unroll
      for (int j = 0; j < 4; ++j)
        bf[j] = *(const bf16x8*)&Bs[(wc * 64 + j * 16 + lrow) * BK + lk];
#pragma unroll
      for (int i = 0; i < 4; ++i)
#pragma unroll
        for (int j = 0; j < 4; ++j)
          acc[i][j] = __builtin_amdgcn_mfma_f32_16x16x32_bf16(af[i], bf[j], acc[i][j], 0, 0, 0);
    }
    __syncthreads();
    cur ^= 1;
  }

  const int lr = (lane >> 4) * 4;
  if constexpr (sizeof(OT) == 2) {
    u16* Ct = smem;                 // [128][132]
#pragma unroll
    for (int i = 0; i < 4; ++i)
#pragma unroll
      for (int j = 0; j < 4; ++j) {
        const int ccol = wc * 64 + j * 16 + lrow;
        float bv = 0.f;
        if constexpr (BIASMODE == 1) bv = bias[col0 + ccol];
#pragma unroll
        for (int r = 0; r < 4; ++r) {
          const int rrow = wr * 64 + i * 16 + lr + r;
          float b2 = bv;
          if constexpr (BIASMODE == 2) b2 = bias[row0 + rrow];
          Ct[rrow * 132 + ccol] = f2bf(acc[i][j][r] + b2);
        }
      }
    __syncthreads();
#pragma unroll
    for (int it = 0; it < 8; ++it) {
      const int id = it * 256 + t;
      const int row = id >> 4, c16 = (id & 15) * 8;
      *(bf16x8*)((u16*)C + (size_t)(row0 + row) * N + col0 + c16) =
          *(const bf16x8*)&Ct[row * 132 + c16];
    }
  } else {
    const int orow = row0 + wr * 64, ocol = col0 + wc * 64;
#pragma unroll
    for (int i = 0; i < 4; ++i)
#pragma unroll
      for (int j = 0; j < 4; ++j) {
        const int cc2 = ocol + j * 16 + lrow;
        float bv = 0.f;
        if constexpr (BIASMODE == 1) bv = bias[cc2];
#pragma unroll
        for (int r = 0; r < 4; ++r) {
          const int rr = orow + i * 16 + lr + r;
          float b2 = bv;
          if constexpr (BIASMODE == 2) b2 = bias[rr];
          C[(size_t)rr * N + cc2] = acc[i][j][r] + b2;
        }
      }
  }
}

// ============================================================================
// reduceG: Gbf[b][i][j] = bf16( sum_p Gpart[b][p][upper(i,j)] )  (symmetric)
// ============================================================================
__global__ __launch_bounds__(256)
void reduceG(const float* __restrict__ Gp, u16* __restrict__ Gbf) {
  const int b = blockIdx.y;
  const int e = blockIdx.x * 256 + threadIdx.x;
  const int i = e / CC, j = e % CC;
  const int ee = (i <= j) ? e : (j * CC + i);
  const float* s = Gp + (size_t)b * 4 * 147456 + ee;
  Gbf[(size_t)b * 147456 + e] =
      f2bf(s[0] + s[147456] + s[2 * 147456] + s[3 * 147456]);
}

// ============================================================================
// s_softmax: per (b,h): S = M1_h @ Uk_h^T + rank-1 terms, *N^-0.5, softmax;
// AU = attn @ Uv_h -> AUb rows (i*8+h); rbias = attn @ bv'
// ============================================================================
__global__ __launch_bounds__(256)
void s_softmax(const u16* __restrict__ M1g, const u16* __restrict__ Wf,
               const float* __restrict__ bf_, const float* __restrict__ P,
               const u16* __restrict__ UvT, u16* __restrict__ AUb,
               float* __restrict__ rbias) {
  __shared__ float Sf[48 * 52];
  __shared__ __align__(16) u16 att[48 * 56];
  const int bh = blockIdx.x, b = bh >> 3, h = bh & 7;
  const int t = threadIdx.x, wid = t >> 6, lane = t & 63;
  const int lrow = lane & 15, lkq = lane >> 4;

  if (wid < 3) {
    f32x4 acc[3] = {};
    const u16* Arow = M1g + (size_t)b * 147456 + (size_t)(h * 48 + wid * 16 + lrow) * CC;
    const u16* Brow = Wf + (size_t)(CC + h * 48) * CC;    // Uk
    for (int ks = 0; ks < 12; ++ks) {
      const int k = ks * 32 + lkq * 8;
      const bf16x8 af = *(const bf16x8*)(Arow + k);
#pragma unroll
      for (int j = 0; j < 3; ++j) {
        const bf16x8 bfr = *(const bf16x8*)(Brow + (size_t)(j * 16 + lrow) * CC + k);
        acc[j] = __builtin_amdgcn_mfma_f32_16x16x32_bf16(af, bfr, acc[j], 0, 0, 0);
      }
    }
    const int lr = lkq * 4;
#pragma unroll
    for (int j = 0; j < 3; ++j)
#pragma unroll
      for (int r = 0; r < 4; ++r)
        Sf[(wid * 16 + lr + r) * 52 + j * 16 + lrow] = acc[j][r];
  }
  __syncthreads();

  if (t < 48) {
    const float bi = bf_[h * 48 + t];
    const float pq = P[b * 768 + h * 48 + t];
    float row[48];
    float mx = -1e30f;
#pragma unroll
    for (int j = 0; j < 48; ++j) {
      const float g = bf_[CC + h * 48 + j];
      const float pk = P[b * 768 + CC + h * 48 + j];
      const float s = (Sf[t * 52 + j] + bi * pk + pq * g + 4096.f * bi * g) * 0.015625f;
      row[j] = s;
      mx = fmaxf(mx, s);
    }
    float sum = 0.f;
#pragma unroll
    for (int j = 0; j < 48; ++j) { row[j] = __expf(row[j] - mx); sum += row[j]; }
    const float inv = 1.f / sum;
    float rb = 0.f;
#pragma unroll
    for (int j = 0; j < 48; ++j) {
      const float a = row[j] * inv;
      att[t * 56 + j] = f2bf(a);
      rb += a * bf_[2 * CC + h * 48 + j];
    }
#pragma unroll
    for (int j = 48; j < 56; ++j) att[t * 56 + j] = 0;
    rbias[b * CC + t * 8 + h] = rb;
  }
  __syncthreads();

  f32x4 acc[3][6] = {};
  const u16* Vbase = UvT + h * 48;
  const bf16x8 z = {};
#pragma unroll
  for (int kk = 0; kk < 2; ++kk) {
    const int k = kk * 32 + lkq * 8;
    bf16x8 af[3];
#pragma unroll
    for (int i = 0; i < 3; ++i) {
      af[i] = *(const bf16x8*)&att[(i * 16 + lrow) * 56 + k];
      if (k >= 48) af[i] = z;
    }
#pragma unroll
    for (int ct = 0; ct < 6; ++ct) {
      const int c = wid * 96 + ct * 16 + lrow;
      bf16x8 bfr = *(const bf16x8*)(Vbase + (size_t)c * CC + k);
      if (k >= 48) bfr = z;
#pragma unroll
      for (int i = 0; i < 3; ++i)
        acc[i][ct] = __builtin_amdgcn_mfma_f32_16x16x32_bf16(af[i], bfr, acc[i][ct], 0, 0, 0);
    }
  }
  const int lr = lkq * 4;
#pragma unroll
  for (int i = 0; i < 3; ++i)
#pragma unroll
    for (int ct = 0; ct < 6; ++ct) {
      const int c = wid * 96 + ct * 16 + lrow;
#pragma unroll
      for (int r = 0; r < 4; ++r) {
        const int ii = i * 16 + lr + r;
        AUb[(size_t)b * 147456 + (size_t)(ii * 8 + h) * CC + c] = f2bf(acc[i][ct][r]);
      }
    }
}

// ============================================================================
extern "C" void kernel_launch(void* const* d_in, const int* in_sizes, int n_in,
                              void* d_out, int out_size, void* d_ws, size_t ws_size,
                              hipStream_t stream) {
  const float* x      = (const float*)d_in[0];
  const float* conv_w = (const float*)d_in[1];
  const float* conv_b = (const float*)d_in[2];
  const float* wq     = (const float*)d_in[3];
  const float* bq     = (const float*)d_in[4];
  const float* wkv    = (const float*)d_in[5];
  const float* bkv    = (const float*)d_in[6];
  const float* wp     = (const float*)d_in[7];
  const float* bp     = (const float*)d_in[8];
  float* y = (float*)d_out;

  char* ws = (char*)d_ws;
  u16*   Wf    = (u16*)(ws + 0);              //   884,736
  float* bf_   = (float*)(ws + 884736);       //     4,608
  u16*   wpb   = (u16*)(ws + 889344);         //   294,912
  u16*   UvT   = (u16*)(ws + 1184256);        //   294,912
  float* sx    = (float*)(ws + 1479168);      //    24,576
  float* P     = (float*)(ws + 1503744);      //    49,152
  float* rb    = (float*)(ws + 1552896);      //    24,576
  u16*   M1g   = (u16*)(ws + 1577472);        // 4,718,592
  u16*   Gbf   = (u16*)(ws + 6296064);        // 4,718,592
  u16*   AUb   = (u16*)(ws + 11014656);       // 4,718,592
  float* Gpart = (float*)(ws + 15733248);     // 37,748,736
  u16*   xb    = (u16*)(ws + 53481984);       // 50,331,648
  u16*   xbT   = (u16*)(ws + 103813632);      // 50,331,648 (dead after gram)
  u16*   R     = xbT;                         // aliases xbT
  // total ws use: 154,145,280 B

  convert_x<<<dim3(6, 64, 16), dim3(256), 0, stream>>>(x, xb, xbT);
  f32_to_bf16<<<dim3(72), dim3(256), 0, stream>>>(wp, wpb, (CC * CC) / 8);
  fuse_weights<<<dim3(72), dim3(384), 0, stream>>>(conv_w, conv_b, wq, bq,
                                                   wkv, bkv, Wf, UvT, bf_);
  colsum<<<dim3(24, 16), dim3(256), 0, stream>>>(xbT, sx);
  proj_sx<<<dim3(6, 16), dim3(128), 0, stream>>>(Wf, sx, P);
  // Gram partials (symmetric: 6 upper tiles only), split-K 4
  gemm_f<float, 0, 1><<<dim3(384), dim3(256), 0, stream>>>(
      xbT, xbT, nullptr, Gpart, CC, CC, NN, 1024, 3, 3, 24,
      (long)CC * NN, (long)CC * NN, 4L * 147456, 147456, 0);
  reduceG<<<dim3(576, 16), dim3(256), 0, stream>>>(Gpart, Gbf);
  // M1g[b] = Uq @ Gx_b
  gemm_f<u16, 0><<<dim3(144), dim3(256), 0, stream>>>(
      Wf, Gbf, nullptr, M1g, CC, CC, CC, CC, 3, 3, 9,
      0, 147456, 147456, 0, 0);
  s_softmax<<<dim3(128), dim3(256), 0, stream>>>(M1g, Wf, bf_, P, UvT, AUb, rb);
  // R[b] = AUb[b] @ xb_b^T + rbias (row-bias)
  gemm_f<u16, 2><<<dim3(1536), dim3(256), 0, stream>>>(
      AUb, xb, rb, R, CC, NN, CC, CC, 32, 3, 96,
      147456, (long)NN * CC, (long)NN * CC, 0, CC);
  // y = R @ wpb^T + bp
  gemm_f<float, 1><<<dim3(1536), dim3(256), 0, stream>>>(
      R, wpb, bp, y, BB * NN, CC, CC, CC, 3, 512, 1536,
      0, 0, 0, 0, 0);
}

// Round 6
// 226.100 us; speedup vs baseline: 1.6393x; 1.1535x over previous
//
#include <hip/hip_runtime.h>
#include <hip/hip_bf16.h>
#include <stdint.h>

#define DEVI static __device__ __forceinline__

typedef __attribute__((ext_vector_type(4))) float f32x4;
typedef __attribute__((ext_vector_type(8))) short bf16x8;
typedef unsigned short u16;
typedef unsigned int u32;
typedef unsigned long long u64;

// B=16, N=4096, C=384, H=8, D=48
#define BB 16
#define NN 4096
#define CC 384
#define HH 8
#define DD 48

DEVI u16 f2bf(float f) {
  union { float f; u32 u; } c; c.f = f;
  u32 u = c.u;
  u32 r = (u + 0x7FFFu + ((u >> 16) & 1u)) >> 16;
  return (u16)r;
}
DEVI float bf2f(u16 h) {
  union { float f; u32 u; } c; c.u = ((u32)h) << 16;
  return c.f;
}
DEVI void stage8(u16* dst, const float* src) {
  const f32x4 a = *(const f32x4*)(src);
  const f32x4 b = *(const f32x4*)(src + 4);
  union { bf16x8 v; u16 u[8]; } o;
  o.u[0] = f2bf(a[0]); o.u[1] = f2bf(a[1]); o.u[2] = f2bf(a[2]); o.u[3] = f2bf(a[3]);
  o.u[4] = f2bf(b[0]); o.u[5] = f2bf(b[1]); o.u[6] = f2bf(b[2]); o.u[7] = f2bf(b[3]);
  *(bf16x8*)dst = o.v;
}

typedef const __attribute__((address_space(1))) void* gas_ptr;
typedef __attribute__((address_space(3))) void* las_ptr;
DEVI void gload16(const void* g, void* l) {
  __builtin_amdgcn_global_load_lds((gas_ptr)g, (las_ptr)l, 16, 0, 0);
}

// ============================================================================
// fp32 -> bf16 bulk convert
// ============================================================================
__global__ __launch_bounds__(256)
void f32_to_bf16(const float* __restrict__ in, u16* __restrict__ out, int n8) {
  const int i = blockIdx.x * 256 + threadIdx.x;
  if (i >= n8) return;
  u16 tmp[8];
  stage8(tmp, in + (size_t)i * 8);
  *(bf16x8*)(out + (size_t)i * 8) = *(bf16x8*)tmp;
}

// ============================================================================
// x (f32 [B,N,C]) -> xb bf16 [B,N,C]  AND  xbT bf16 [B,C,N]  (fused transpose)
// ============================================================================
__global__ __launch_bounds__(256)
void convert_x(const float* __restrict__ x, u16* __restrict__ xb,
               u16* __restrict__ xbT) {
  __shared__ __align__(8) u16 Lt[64 * 68];
  const int ct = blockIdx.x, nt = blockIdx.y, b = blockIdx.z;
  const int t = threadIdx.x;
  const int n0 = nt * 64, c0 = ct * 64;
#pragma unroll
  for (int it = 0; it < 4; ++it) {
    const int row = it * 16 + (t >> 4), col = (t & 15) * 4;
    const f32x4 v = *(const f32x4*)&x[((size_t)(b * NN + n0 + row)) * CC + c0 + col];
    u64 pk = (u64)f2bf(v[0]) | ((u64)f2bf(v[1]) << 16) |
             ((u64)f2bf(v[2]) << 32) | ((u64)f2bf(v[3]) << 48);
    *(u64*)(&Lt[row * 68 + col]) = pk;
  }
  __syncthreads();
#pragma unroll
  for (int it = 0; it < 2; ++it) {      // write xb (row-major)
    const int v = it * 256 + t, row = v >> 3, cg = v & 7;
    union { bf16x8 o; u64 q[2]; } u;
    u.q[0] = *(const u64*)(&Lt[row * 68 + cg * 8]);
    u.q[1] = *(const u64*)(&Lt[row * 68 + cg * 8 + 4]);
    *(bf16x8*)&xb[((size_t)(b * NN + n0 + row)) * CC + c0 + cg * 8] = u.o;
  }
#pragma unroll
  for (int it = 0; it < 2; ++it) {      // write xbT (transposed)
    const int v = it * 256 + t, c = v >> 3, ng = v & 7;
    union { bf16x8 o; u16 e[8]; } u;
#pragma unroll
    for (int r = 0; r < 8; ++r) u.e[r] = Lt[(ng * 8 + r) * 68 + c];
    *(bf16x8*)&xbT[((size_t)(b * CC + c0 + c)) * NN + n0 + ng * 8] = u.o;
  }
}

// ============================================================================
// cw (f32 [m=384][c=384]) -> cwT bf16 [c][m]
// ============================================================================
__global__ __launch_bounds__(256)
void transpose_cw(const float* __restrict__ cw, u16* __restrict__ cwT) {
  __shared__ __align__(8) u16 Lt[64 * 68];
  const int mt = blockIdx.x, ct = blockIdx.y;
  const int t = threadIdx.x;
  const int m0 = mt * 64, c0 = ct * 64;
#pragma unroll
  for (int it = 0; it < 4; ++it) {
    const int row = it * 16 + (t >> 4), col = (t & 15) * 4;
    const f32x4 v = *(const f32x4*)&cw[(size_t)(m0 + row) * CC + c0 + col];
    u64 pk = (u64)f2bf(v[0]) | ((u64)f2bf(v[1]) << 16) |
             ((u64)f2bf(v[2]) << 32) | ((u64)f2bf(v[3]) << 48);
    *(u64*)(&Lt[row * 68 + col]) = pk;
  }
  __syncthreads();
#pragma unroll
  for (int it = 0; it < 2; ++it) {
    const int v = it * 256 + t, c = v >> 3, mg = v & 7;
    union { bf16x8 o; u16 e[8]; } u;
#pragma unroll
    for (int r = 0; r < 8; ++r) u.e[r] = Lt[(mg * 8 + r) * 68 + c];
    *(bf16x8*)&cwT[(size_t)(c0 + c) * CC + m0 + mg * 8] = u.o;
  }
}

// ============================================================================
// bias_fuse: bf_[o] = btop[o] + sum_m wtop[o][m]*cb[m]  (one wave per o)
// ============================================================================
__global__ __launch_bounds__(256)
void bias_fuse(const float* __restrict__ wq, const float* __restrict__ bq,
               const float* __restrict__ wkv, const float* __restrict__ bkv,
               const float* __restrict__ cb, float* __restrict__ bf_) {
  const int o = blockIdx.x * 4 + (threadIdx.x >> 6);   // 288 blocks x 4 waves
  const int lane = threadIdx.x & 63;
  const float* wrow;
  float b0;
  if (o < CC) { wrow = wq + (size_t)o * CC;        b0 = bq[o]; }
  else        { wrow = wkv + (size_t)(o - CC) * CC; b0 = bkv[o - CC]; }
  float s = 0.f;
  for (int m = lane; m < CC; m += 64) s += wrow[m] * cb[m];
#pragma unroll
  for (int off = 32; off; off >>= 1) s += __shfl_xor(s, off, 64);
  if (lane == 0) bf_[o] = b0 + s;
}

// ============================================================================
// colsum: sx[b][c] = sum_n xbT[b][c][n]
// ============================================================================
__global__ __launch_bounds__(256)
void colsum(const u16* __restrict__ xbT, float* __restrict__ sx) {
  const int b = blockIdx.y, c = blockIdx.x * 16 + (threadIdx.x >> 4);
  const int sl = threadIdx.x & 15;
  const u16* src = xbT + ((size_t)(b * CC + c)) * NN + sl * 256;
  float s = 0.f;
  for (int i = 0; i < 32; ++i) {
    const bf16x8 v = *(const bf16x8*)(src + i * 8);
#pragma unroll
    for (int r = 0; r < 8; ++r) s += bf2f((u16)v[r]);
  }
#pragma unroll
  for (int m = 1; m < 16; m <<= 1) s += __shfl_xor(s, m, 64);
  if (sl == 0) sx[b * CC + c] = s;
}

// ============================================================================
// proj_sx: P[b][o] = sum_c Wf[o][c] * sx[b][c], o<768
// ============================================================================
__global__ __launch_bounds__(128)
void proj_sx(const u16* __restrict__ Wf, const float* __restrict__ sx,
             float* __restrict__ P) {
  __shared__ float sl[CC];
  const int b = blockIdx.y, o = blockIdx.x * 128 + threadIdx.x;
  for (int i = threadIdx.x; i < CC; i += 128) sl[i] = sx[b * CC + i];
  __syncthreads();
  float acc = 0.f;
  const u16* wr = Wf + (size_t)o * CC;
  for (int c8 = 0; c8 < CC; c8 += 8) {
    const bf16x8 w = *(const bf16x8*)(wr + c8);
#pragma unroll
    for (int r = 0; r < 8; ++r) acc += bf2f((u16)w[r]) * sl[c8 + r];
  }
  P[b * 768 + o] = acc;
}

// ============================================================================
// Generic GEMM: C[M,N](+p partials) = A[M,K-slice] @ W[N,K-slice]^T (+bias)
// TRI: symmetric output (6 upper tiles of 3x3). SWZ: XCD swizzle (grid%8==0).
// ============================================================================
template<typename OT, int BIASMODE, int TRI = 0, int SWZ = 1>
__global__ __launch_bounds__(256)
void gemm_f(const u16* __restrict__ A, const u16* __restrict__ W,
            const float* __restrict__ bias, OT* __restrict__ C,
            int M, int N, int K, int klen, int nbn, int nbm, int tpb,
            long sA, long sW, long sC, long sCp, long sBias) {
  constexpr int BK = 64;
  __shared__ __align__(16) u16 smem[32768];   // 64 KB: 2 x (As 8192 | Bs 8192)

  const int nx = gridDim.x;
  const int lin = blockIdx.x;
  const int lin2 = SWZ ? (lin & 7) * (nx >> 3) + (lin >> 3) : lin;
  const int b = lin2 / tpb;
  int t2 = lin2 % tpb;
  int bn, bm, p;
  if constexpr (TRI) {
    const int tl = t2 % 6; p = t2 / 6;
    bm = tl < 3 ? 0 : (tl < 5 ? 1 : 2);
    bn = tl < 3 ? tl : (tl < 5 ? tl - 2 : 2);
  } else {
    bn = t2 % nbn; t2 /= nbn;
    bm = t2 % nbm;
    p = t2 / nbm;
  }
  A += (size_t)b * sA; W += (size_t)b * sW;
  C += (size_t)b * sC + (size_t)p * sCp;
  if (BIASMODE) bias += (size_t)b * sBias;

  const int t = threadIdx.x;
  const int wid = t >> 6, lane = t & 63;
  const int wr = wid >> 1, wc = wid & 1;
  const int row0 = bm * 128, col0 = bn * 128;
  const int lrow = lane & 15;
  const int lswz = (lane & 7) << 3;
  const int kstart = p * klen;

  const int arow = t >> 3;
  const int scol = ((t & 7) ^ ((t >> 3) & 7)) * 8;
  const u16* Ag = A + (size_t)(row0 + arow) * K + scol;
  const u16* Wg = W + (size_t)(col0 + arow) * K + scol;

  f32x4 acc[4][4] = {};
  const int NT = klen >> 6;

  auto stage = [&](int buf, int kt) {
    u16* Al = smem + buf * 16384 + t * 8;
    u16* Bl = smem + buf * 16384 + 8192 + t * 8;
    const int k0 = kstart + kt * BK;
#pragma unroll
    for (int it = 0; it < 4; ++it) {
      gload16(Ag + (size_t)(it * 32) * K + k0, Al + it * 2048);
      gload16(Wg + (size_t)(it * 32) * K + k0, Bl + it * 2048);
    }
  };

  stage(0, 0);
  __syncthreads();
  int cur = 0;
  for (int kt = 0; kt < NT; ++kt) {
    if (kt + 1 < NT) stage(cur ^ 1, kt + 1);
    const u16* As = smem + cur * 16384;
    const u16* Bs = smem + cur * 16384 + 8192;
#pragma unroll
    for (int kk = 0; kk < 2; ++kk) {
      const int lk = (kk * 32 + (lane >> 4) * 8) ^ lswz;
      bf16x8 af[4], bf[4];
#pragma unroll
      for (int i = 0; i < 4; ++i)
        af[i] = *(const bf16x8*)&As[(wr * 64 + i * 16 + lrow) * BK + lk];
#pragma unroll
      for (int j = 0; j < 4; ++j)
        bf[j] = *(const bf16x8*)&Bs[(wc * 64 + j * 16 + lrow) * BK + lk];
#pragma unroll
      for (int i = 0; i < 4; ++i)
#pragma unroll
        for (int j = 0; j < 4; ++j)
          acc[i][j] = __builtin_amdgcn_mfma_f32_16x16x32_bf16(af[i], bf[j], acc[i][j], 0, 0, 0);
    }
    __syncthreads();
    cur ^= 1;
  }

  const int lr = (lane >> 4) * 4;
  if constexpr (sizeof(OT) == 2) {
    u16* Ct = smem;                 // [128][132]
#pragma unroll
    for (int i = 0; i < 4; ++i)
#pragma unroll
      for (int j = 0; j < 4; ++j) {
        const int ccol = wc * 64 + j * 16 + lrow;
        float bv = 0.f;
        if constexpr (BIASMODE == 1) bv = bias[col0 + ccol];
#pragma unroll
        for (int r = 0; r < 4; ++r) {
          const int rrow = wr * 64 + i * 16 + lr + r;
          float b2 = bv;
          if constexpr (BIASMODE == 2) b2 = bias[row0 + rrow];
          Ct[rrow * 132 + ccol] = f2bf(acc[i][j][r] + b2);
        }
      }
    __syncthreads();
#pragma unroll
    for (int it = 0; it < 8; ++it) {
      const int id = it * 256 + t;
      const int row = id >> 4, c16 = (id & 15) * 8;
      *(bf16x8*)((u16*)C + (size_t)(row0 + row) * N + col0 + c16) =
          *(const bf16x8*)&Ct[row * 132 + c16];
    }
  } else {
    const int orow = row0 + wr * 64, ocol = col0 + wc * 64;
#pragma unroll
    for (int i = 0; i < 4; ++i)
#pragma unroll
      for (int j = 0; j < 4; ++j) {
        const int cc2 = ocol + j * 16 + lrow;
        float bv = 0.f;
        if constexpr (BIASMODE == 1) bv = bias[cc2];
#pragma unroll
        for (int r = 0; r < 4; ++r) {
          const int rr = orow + i * 16 + lr + r;
          float b2 = bv;
          if constexpr (BIASMODE == 2) b2 = bias[rr];
          C[(size_t)rr * N + cc2] = acc[i][j][r] + b2;
        }
      }
  }
}

// ============================================================================
// reduceG: Gbf[b][i][j] = bf16( sum_p Gpart[b][p][upper(i,j)] )  (symmetric)
// ============================================================================
__global__ __launch_bounds__(256)
void reduceG(const float* __restrict__ Gp, u16* __restrict__ Gbf) {
  const int b = blockIdx.y;
  const int e = blockIdx.x * 256 + threadIdx.x;
  const int i = e / CC, j = e % CC;
  const int ee = (i <= j) ? e : (j * CC + i);
  const float* s = Gp + (size_t)b * 4 * 147456 + ee;
  Gbf[(size_t)b * 147456 + e] =
      f2bf(s[0] + s[147456] + s[2 * 147456] + s[3 * 147456]);
}

// ============================================================================
// s_softmax: per (b,h): S = M1_h @ Uk_h^T + rank-1 terms, *N^-0.5, softmax;
// AU = attn @ Uv_h -> AUb rows (i*8+h); rbias = attn @ bv'
// ============================================================================
__global__ __launch_bounds__(256)
void s_softmax(const u16* __restrict__ M1g, const u16* __restrict__ Wf,
               const float* __restrict__ bf_, const float* __restrict__ P,
               const u16* __restrict__ UvT, u16* __restrict__ AUb,
               float* __restrict__ rbias) {
  __shared__ float Sf[48 * 52];
  __shared__ __align__(16) u16 att[48 * 56];
  const int bh = blockIdx.x, b = bh >> 3, h = bh & 7;
  const int t = threadIdx.x, wid = t >> 6, lane = t & 63;
  const int lrow = lane & 15, lkq = lane >> 4;

  if (wid < 3) {
    f32x4 acc[3] = {};
    const u16* Arow = M1g + (size_t)b * 147456 + (size_t)(h * 48 + wid * 16 + lrow) * CC;
    const u16* Brow = Wf + (size_t)(CC + h * 48) * CC;    // Uk
    for (int ks = 0; ks < 12; ++ks) {
      const int k = ks * 32 + lkq * 8;
      const bf16x8 af = *(const bf16x8*)(Arow + k);
#pragma unroll
      for (int j = 0; j < 3; ++j) {
        const bf16x8 bfr = *(const bf16x8*)(Brow + (size_t)(j * 16 + lrow) * CC + k);
        acc[j] = __builtin_amdgcn_mfma_f32_16x16x32_bf16(af, bfr, acc[j], 0, 0, 0);
      }
    }
    const int lr = lkq * 4;
#pragma unroll
    for (int j = 0; j < 3; ++j)
#pragma unroll
      for (int r = 0; r < 4; ++r)
        Sf[(wid * 16 + lr + r) * 52 + j * 16 + lrow] = acc[j][r];
  }
  __syncthreads();

  if (t < 48) {
    const float bi = bf_[h * 48 + t];
    const float pq = P[b * 768 + h * 48 + t];
    float row[48];
    float mx = -1e30f;
#pragma unroll
    for (int j = 0; j < 48; ++j) {
      const float g = bf_[CC + h * 48 + j];
      const float pk = P[b * 768 + CC + h * 48 + j];
      const float s = (Sf[t * 52 + j] + bi * pk + pq * g + 4096.f * bi * g) * 0.015625f;
      row[j] = s;
      mx = fmaxf(mx, s);
    }
    float sum = 0.f;
#pragma unroll
    for (int j = 0; j < 48; ++j) { row[j] = __expf(row[j] - mx); sum += row[j]; }
    const float inv = 1.f / sum;
    float rb = 0.f;
#pragma unroll
    for (int j = 0; j < 48; ++j) {
      const float a = row[j] * inv;
      att[t * 56 + j] = f2bf(a);
      rb += a * bf_[2 * CC + h * 48 + j];
    }
#pragma unroll
    for (int j = 48; j < 56; ++j) att[t * 56 + j] = 0;
    rbias[b * CC + t * 8 + h] = rb;
  }
  __syncthreads();

  f32x4 acc[3][6] = {};
  const u16* Vbase = UvT + h * 48;
  const bf16x8 z = {};
#pragma unroll
  for (int kk = 0; kk < 2; ++kk) {
    const int k = kk * 32 + lkq * 8;
    bf16x8 af[3];
#pragma unroll
    for (int i = 0; i < 3; ++i) {
      af[i] = *(const bf16x8*)&att[(i * 16 + lrow) * 56 + k];
      if (k >= 48) af[i] = z;
    }
#pragma unroll
    for (int ct = 0; ct < 6; ++ct) {
      const int c = wid * 96 + ct * 16 + lrow;
      bf16x8 bfr = *(const bf16x8*)(Vbase + (size_t)c * CC + k);
      if (k >= 48) bfr = z;
#pragma unroll
      for (int i = 0; i < 3; ++i)
        acc[i][ct] = __builtin_amdgcn_mfma_f32_16x16x32_bf16(af[i], bfr, acc[i][ct], 0, 0, 0);
    }
  }
  const int lr = lkq * 4;
#pragma unroll
  for (int i = 0; i < 3; ++i)
#pragma unroll
    for (int ct = 0; ct < 6; ++ct) {
      const int c = wid * 96 + ct * 16 + lrow;
#pragma unroll
      for (int r = 0; r < 4; ++r) {
        const int ii = i * 16 + lr + r;
        AUb[(size_t)b * 147456 + (size_t)(ii * 8 + h) * CC + c] = f2bf(acc[i][ct][r]);
      }
    }
}

// ============================================================================
extern "C" void kernel_launch(void* const* d_in, const int* in_sizes, int n_in,
                              void* d_out, int out_size, void* d_ws, size_t ws_size,
                              hipStream_t stream) {
  const float* x      = (const float*)d_in[0];
  const float* conv_w = (const float*)d_in[1];
  const float* conv_b = (const float*)d_in[2];
  const float* wq     = (const float*)d_in[3];
  const float* bq     = (const float*)d_in[4];
  const float* wkv    = (const float*)d_in[5];
  const float* bkv    = (const float*)d_in[6];
  const float* wp     = (const float*)d_in[7];
  const float* bp     = (const float*)d_in[8];
  float* y = (float*)d_out;

  char* ws = (char*)d_ws;
  u16*   Wf    = (u16*)(ws + 0);              //   884,736 (rows 768+ unused)
  float* bf_   = (float*)(ws + 884736);       //     4,608
  u16*   wpb   = (u16*)(ws + 889344);         //   294,912
  u16*   UvT   = (u16*)(ws + 1184256);        //   294,912
  float* sx    = (float*)(ws + 1479168);      //    24,576
  float* P     = (float*)(ws + 1503744);      //    49,152
  float* rb    = (float*)(ws + 1552896);      //    24,576
  u16*   M1g   = (u16*)(ws + 1577472);        // 4,718,592
  u16*   Gbf   = (u16*)(ws + 6296064);        // 4,718,592
  u16*   AUb   = (u16*)(ws + 11014656);       // 4,718,592
  float* Gpart = (float*)(ws + 15733248);     // 37,748,736
  u16*   wtopb = (u16*)(ws + 53481984);       //   884,736  [wq;wkv] bf16
  u16*   cwTb  = (u16*)(ws + 54366720);       //   294,912  cw^T bf16
  u16*   xb    = (u16*)(ws + 54661632);       // 50,331,648
  u16*   xbT   = (u16*)(ws + 104993280);      // 50,331,648 (dead after gram)
  u16*   R     = xbT;                         // aliases xbT
  // total ws use: 155,324,928 B

  convert_x<<<dim3(6, 64, 16), dim3(256), 0, stream>>>(x, xb, xbT);
  f32_to_bf16<<<dim3(72), dim3(256), 0, stream>>>(wp, wpb, (CC * CC) / 8);
  f32_to_bf16<<<dim3(72), dim3(256), 0, stream>>>(wq, wtopb, (CC * CC) / 8);
  f32_to_bf16<<<dim3(144), dim3(256), 0, stream>>>(wkv, wtopb + CC * CC,
                                                   (2 * CC * CC) / 8);
  transpose_cw<<<dim3(6, 6), dim3(256), 0, stream>>>(conv_w, cwTb);
  bias_fuse<<<dim3(288), dim3(256), 0, stream>>>(wq, bq, wkv, bkv, conv_b, bf_);
  // Wf[0:768] = wtop @ cw : C[o][c] = sum_m wtopb[o][m]*cwTb[c][m]
  gemm_f<u16, 0, 0, 0><<<dim3(18), dim3(256), 0, stream>>>(
      wtopb, cwTb, nullptr, Wf, 2 * CC, CC, CC, CC, 3, 6, 18,
      0, 0, 0, 0, 0);
  // UvT[c][j] = sum_m cwTb[c][m]*wkv_v[j][m]  (wkv_v = wtopb rows 768+)
  gemm_f<u16, 0, 0, 0><<<dim3(9), dim3(256), 0, stream>>>(
      cwTb, wtopb + 2 * CC * CC, nullptr, UvT, CC, CC, CC, CC, 3, 3, 9,
      0, 0, 0, 0, 0);
  colsum<<<dim3(24, 16), dim3(256), 0, stream>>>(xbT, sx);
  proj_sx<<<dim3(6, 16), dim3(128), 0, stream>>>(Wf, sx, P);
  // Gram partials (symmetric: 6 upper tiles only), split-K 4
  gemm_f<float, 0, 1><<<dim3(384), dim3(256), 0, stream>>>(
      xbT, xbT, nullptr, Gpart, CC, CC, NN, 1024, 3, 3, 24,
      (long)CC * NN, (long)CC * NN, 4L * 147456, 147456, 0);
  reduceG<<<dim3(576, 16), dim3(256), 0, stream>>>(Gpart, Gbf);
  // M1g[b] = Uq @ Gx_b
  gemm_f<u16, 0><<<dim3(144), dim3(256), 0, stream>>>(
      Wf, Gbf, nullptr, M1g, CC, CC, CC, CC, 3, 3, 9,
      0, 147456, 147456, 0, 0);
  s_softmax<<<dim3(128), dim3(256), 0, stream>>>(M1g, Wf, bf_, P, UvT, AUb, rb);
  // R[b] = AUb[b] @ xb_b^T + rbias (row-bias)
  gemm_f<u16, 2><<<dim3(1536), dim3(256), 0, stream>>>(
      AUb, xb, rb, R, CC, NN, CC, CC, 32, 3, 96,
      147456, (long)NN * CC, (long)NN * CC, 0, CC);
  // y = R @ wpb^T + bp
  gemm_f<float, 1><<<dim3(1536), dim3(256), 0, stream>>>(
      R, wpb, bp, y, BB * NN, CC, CC, CC, 3, 512, 1536,
      0, 0, 0, 0, 0);
}